// Round 3
// baseline (1355.049 us; speedup 1.0000x reference)
//
#include <hip/hip_runtime.h>

#define Hh 128
#define Ww 128
#define HW 16384
#define Cc 512
#define CQ 64

// ---------------- prep: transpose dwconv weights to (tap, C) + fused bias ----------------
// wt rows: 0..48 = w7 taps, 49..73 = w5 taps, 74..82 = w3 taps, 83 = b7+b5+b3
__global__ void prep_weights(const float* __restrict__ w7, const float* __restrict__ b7,
                             const float* __restrict__ w5, const float* __restrict__ b5,
                             const float* __restrict__ w3, const float* __restrict__ b3,
                             float* __restrict__ wt)
{
    int c = blockIdx.x * 256 + threadIdx.x;
    if (c >= Cc) return;
    for (int t = 0; t < 49; ++t) wt[t*Cc + c] = w7[c*49 + t];
    for (int t = 0; t < 25; ++t) wt[(49+t)*Cc + c] = w5[c*25 + t];
    for (int t = 0; t <  9; ++t) wt[(74+t)*Cc + c] = w3[c*9 + t];
    wt[83*Cc + c] = b7[c] + b5[c] + b3[c];
}

// ---------------- fused QKV GEMM ----------------
// src (2,HW,512) row-major (channel-last). q,k: (2,HW,64); v: (2,HW,512). Bias added.
// out[n,o] = sum_c src[n,c]*W[o,c] + bias[o]
__global__ __launch_bounds__(256) void qkv_gemm(
    const float* __restrict__ src,
    const float* __restrict__ wq, const float* __restrict__ bq,
    const float* __restrict__ wk, const float* __restrict__ bk,
    const float* __restrict__ wv, const float* __restrict__ bv,
    float* __restrict__ qo, float* __restrict__ ko, float* __restrict__ vo)
{
    const int b  = blockIdx.z;
    const int m0 = blockIdx.x * 128;
    const int n0 = blockIdx.y * 64;   // global output channel tile: 0..639

    const float* Wm; const float* bias; float* Out; int oc; int nr;
    if (n0 < 64)       { Wm = wq; bias = bq; Out = qo + (size_t)b*HW*CQ; oc = CQ; nr = 0; }
    else if (n0 < 128) { Wm = wk; bias = bk; Out = ko + (size_t)b*HW*CQ; oc = CQ; nr = 0; }
    else               { Wm = wv; bias = bv; Out = vo + (size_t)b*HW*Cc; oc = Cc; nr = n0 - 128; }

    __shared__ float As[16][132];   // [kk][m] transposed
    __shared__ float Bs[16][68];    // [kk][n] transposed

    const int tid = threadIdx.x;
    const int tx = tid & 15;    // n dir, 4 outputs each
    const int ty = tid >> 4;    // m dir, 8 outputs each
    const float* srcb = src + (size_t)b*HW*Cc;

    float acc[8][4];
    #pragma unroll
    for (int i = 0; i < 8; ++i)
        #pragma unroll
        for (int j = 0; j < 4; ++j) acc[i][j] = 0.f;

    for (int k0 = 0; k0 < Cc; k0 += 16) {
        __syncthreads();
        #pragma unroll
        for (int r = 0; r < 2; ++r) {
            int t = tid + r*256;
            int row = t >> 2;            // 0..127
            int c4  = (t & 3) * 4;
            float4 a = *(const float4*)&srcb[(size_t)(m0+row)*Cc + k0 + c4];
            As[c4+0][row] = a.x; As[c4+1][row] = a.y; As[c4+2][row] = a.z; As[c4+3][row] = a.w;
        }
        {
            int row = tid >> 2;          // 0..63
            int c4  = (tid & 3) * 4;
            float4 w4 = *(const float4*)&Wm[(size_t)(nr+row)*Cc + k0 + c4];
            Bs[c4+0][row] = w4.x; Bs[c4+1][row] = w4.y; Bs[c4+2][row] = w4.z; Bs[c4+3][row] = w4.w;
        }
        __syncthreads();
        #pragma unroll
        for (int kk = 0; kk < 16; ++kk) {
            float a0[8], b0[4];
            #pragma unroll
            for (int i = 0; i < 8; ++i) a0[i] = As[kk][ty*8+i];
            #pragma unroll
            for (int j = 0; j < 4; ++j) b0[j] = Bs[kk][tx*4+j];
            #pragma unroll
            for (int i = 0; i < 8; ++i)
                #pragma unroll
                for (int j = 0; j < 4; ++j) acc[i][j] = fmaf(a0[i], b0[j], acc[i][j]);
        }
    }

    #pragma unroll
    for (int i = 0; i < 8; ++i) {
        int m = m0 + ty*8 + i;
        float4 o;
        o.x = acc[i][0] + bias[nr + tx*4 + 0];
        o.y = acc[i][1] + bias[nr + tx*4 + 1];
        o.z = acc[i][2] + bias[nr + tx*4 + 2];
        o.w = acc[i][3] + bias[nr + tx*4 + 3];
        *(float4*)&Out[(size_t)m*oc + nr + tx*4] = o;
    }
}

// ---------------- criss-cross scores ----------------
// e layout: e[((b*2+mode)*128 + L)*16384 + r*128 + k]
// mode0 (column j=L): e[i][k] = sum_c q[n=i*W+L][c] * k[n=k*W+L][c]
// mode1 (row    i=L): e[j][k] = sum_c q[n=L*W+j][c] * k[n=L*W+k][c]
__global__ __launch_bounds__(256) void cc_scores(
    const float* __restrict__ qi, const float* __restrict__ ki, float* __restrict__ e)
{
    const int L = blockIdx.x;
    const int mode = blockIdx.y;
    const int b = blockIdx.z;
    const float* qb = qi + (size_t)b*HW*CQ;
    const float* kb = ki + (size_t)b*HW*CQ;
    float* eb = e + ((size_t)((b*2+mode)*128 + L)) * 16384;

    __shared__ float Qs[16][132];
    __shared__ float Ks[16][132];
    const int tid = threadIdx.x;
    const int tx = tid & 15, ty = tid >> 4;

    float acc[8][8];
    #pragma unroll
    for (int i = 0; i < 8; ++i)
        #pragma unroll
        for (int j = 0; j < 8; ++j) acc[i][j] = 0.f;

    for (int c0 = 0; c0 < CQ; c0 += 16) {
        __syncthreads();
        #pragma unroll
        for (int r = 0; r < 2; ++r) {
            int t = tid + r*256;
            int row = t >> 2;
            int c4  = (t & 3) * 4;
            int n = (mode == 0) ? row*Ww + L : L*Ww + row;
            float4 a = *(const float4*)&qb[(size_t)n*CQ + c0 + c4];
            Qs[c4+0][row] = a.x; Qs[c4+1][row] = a.y; Qs[c4+2][row] = a.z; Qs[c4+3][row] = a.w;
            float4 kk4 = *(const float4*)&kb[(size_t)n*CQ + c0 + c4];
            Ks[c4+0][row] = kk4.x; Ks[c4+1][row] = kk4.y; Ks[c4+2][row] = kk4.z; Ks[c4+3][row] = kk4.w;
        }
        __syncthreads();
        #pragma unroll
        for (int cc = 0; cc < 16; ++cc) {
            float a0[8], b0[8];
            #pragma unroll
            for (int i = 0; i < 8; ++i) a0[i] = Qs[cc][ty*8+i];
            #pragma unroll
            for (int j = 0; j < 8; ++j) b0[j] = Ks[cc][tx*8+j];
            #pragma unroll
            for (int i = 0; i < 8; ++i)
                #pragma unroll
                for (int j = 0; j < 8; ++j) acc[i][j] = fmaf(a0[i], b0[j], acc[i][j]);
        }
    }

    #pragma unroll
    for (int i = 0; i < 8; ++i) {
        int r = ty*8 + i;
        float4 o0, o1;
        o0.x = acc[i][0]; o0.y = acc[i][1]; o0.z = acc[i][2]; o0.w = acc[i][3];
        o1.x = acc[i][4]; o1.y = acc[i][5]; o1.z = acc[i][6]; o1.w = acc[i][7];
        *(float4*)&eb[r*128 + tx*8 + 0] = o0;
        *(float4*)&eb[r*128 + tx*8 + 4] = o1;
    }
}

// ---------------- softmax over axis i (axis=1 of att!) ----------------
// For each (b, j, k_cat): normalize over the 128 query rows i.
// mode0: elements e[b,0,j][i][k] (stride 128 within block)
// mode1: elements e[b,1,i][j=L][k] (stride 16384 across line-blocks)
__global__ __launch_bounds__(128) void cc_softmax(float* __restrict__ e)
{
    const int L = blockIdx.x, mode = blockIdx.y, b = blockIdx.z;
    const int k = threadIdx.x;
    float* base; int stride;
    if (mode == 0) { base = e + ((size_t)(b*2)*128 + L)*16384 + k;          stride = 128;   }
    else           { base = e + ((size_t)(b*2+1)*128)*16384 + L*128 + k;    stride = 16384; }
    float m = -1e30f, s = 0.f;
    #pragma unroll 8
    for (int i = 0; i < 128; ++i) {
        float val = base[i*stride];
        float mn = fmaxf(m, val);
        s = s*__expf(m - mn) + __expf(val - mn);
        m = mn;
    }
    float inv = 1.f / s;
    #pragma unroll 8
    for (int i = 0; i < 128; ++i) {
        float val = base[i*stride];
        base[i*stride] = __expf(val - m) * inv;
    }
}

// ---------------- fused depthwise 7x7+5x5+3x3 conv + residual ----------------
// out[b,n,c] = x[b,n,c] + sum_taps (channel-last => coalesced along c)
__global__ __launch_bounds__(256) void cnn_resid(
    const float* __restrict__ x, const float* __restrict__ wt, float* __restrict__ out)
{
    const int tid = threadIdx.x;
    const int c0  = (tid & 127) * 4;
    const int pos = blockIdx.x * 2 + (tid >> 7);
    const int b   = blockIdx.z;
    const int i = pos >> 7, j = pos & 127;
    const float* xb = x + (size_t)b*HW*Cc;

    float4 acc = *(const float4*)&wt[83*Cc + c0];       // summed biases
    {
        float4 xv = *(const float4*)&xb[(size_t)pos*Cc + c0];
        acc.x += xv.x; acc.y += xv.y; acc.z += xv.z; acc.w += xv.w;   // residual (feat)
    }
    for (int di = 0; di < 7; ++di) {
        int ii = i + di - 3;
        if (ii < 0 || ii >= Hh) continue;
        for (int dj = 0; dj < 7; ++dj) {
            int jj = j + dj - 3;
            if (jj < 0 || jj >= Ww) continue;
            float4 xv = *(const float4*)&xb[(size_t)(ii*Ww+jj)*Cc + c0];
            float4 w  = *(const float4*)&wt[(di*7+dj)*Cc + c0];
            acc.x = fmaf(xv.x, w.x, acc.x); acc.y = fmaf(xv.y, w.y, acc.y);
            acc.z = fmaf(xv.z, w.z, acc.z); acc.w = fmaf(xv.w, w.w, acc.w);
            if ((unsigned)(di-1) <= 4u && (unsigned)(dj-1) <= 4u) {
                float4 w5 = *(const float4*)&wt[(49 + (di-1)*5 + (dj-1))*Cc + c0];
                acc.x = fmaf(xv.x, w5.x, acc.x); acc.y = fmaf(xv.y, w5.y, acc.y);
                acc.z = fmaf(xv.z, w5.z, acc.z); acc.w = fmaf(xv.w, w5.w, acc.w);
            }
            if ((unsigned)(di-2) <= 2u && (unsigned)(dj-2) <= 2u) {
                float4 w3 = *(const float4*)&wt[(74 + (di-2)*3 + (dj-2))*Cc + c0];
                acc.x = fmaf(xv.x, w3.x, acc.x); acc.y = fmaf(xv.y, w3.y, acc.y);
                acc.z = fmaf(xv.z, w3.z, acc.z); acc.w = fmaf(xv.w, w3.w, acc.w);
            }
        }
    }
    *(float4*)&out[((size_t)b*HW + pos)*Cc + c0] = acc;
}

// ---------------- aggregation: dest = base + gamma * (att @ V)  (per line GEMM) ----------------
// mode0 (col, L=j): out[i][c] over V rows n=k*W+L ; dest = base + g*acc (writes)
// mode1 (row, L=i): out[j][c] over V rows n=L*W+k ; dest += g*acc (RMW; separate launch)
__global__ __launch_bounds__(256) void cc_agg(
    const float* __restrict__ att, const float* __restrict__ v,
    const float* __restrict__ base, float* __restrict__ dest,
    const float* __restrict__ gamma_ptr, const int mode)
{
    const int L  = blockIdx.x;
    const int c0 = blockIdx.y * 128;
    const int b  = blockIdx.z;
    const float* A  = att + ((size_t)((b*2+mode)*128 + L)) * 16384;  // [r][k] 128x128
    const float* vb = v + (size_t)b*HW*Cc;

    __shared__ float As[16][132];  // [kk][r]
    __shared__ float Bs[16][132];  // [kk][c]
    const int tid = threadIdx.x;
    const int tx = tid & 15, ty = tid >> 4;

    float acc[8][8];
    #pragma unroll
    for (int i = 0; i < 8; ++i)
        #pragma unroll
        for (int j = 0; j < 8; ++j) acc[i][j] = 0.f;

    for (int k0 = 0; k0 < 128; k0 += 16) {
        __syncthreads();
        #pragma unroll
        for (int r = 0; r < 2; ++r) {
            int t = tid + r*256;
            int row = t >> 2;            // att row r: 0..127
            int c4  = (t & 3) * 4;
            float4 a = *(const float4*)&A[row*128 + k0 + c4];
            As[c4+0][row] = a.x; As[c4+1][row] = a.y; As[c4+2][row] = a.z; As[c4+3][row] = a.w;

            int rowk = (tid >> 5) + r*8; // V k-row: 0..15
            int cc   = (tid & 31) * 4;
            int nv = (mode == 0) ? (k0+rowk)*Ww + L : L*Ww + (k0+rowk);
            float4 vv = *(const float4*)&vb[(size_t)nv*Cc + c0 + cc];
            *(float4*)&Bs[rowk][cc] = vv;
        }
        __syncthreads();
        #pragma unroll
        for (int kk = 0; kk < 16; ++kk) {
            float a0[8], b0[8];
            #pragma unroll
            for (int i = 0; i < 8; ++i) a0[i] = As[kk][ty*8+i];
            #pragma unroll
            for (int j = 0; j < 8; ++j) b0[j] = Bs[kk][tx*8+j];
            #pragma unroll
            for (int i = 0; i < 8; ++i)
                #pragma unroll
                for (int j = 0; j < 8; ++j) acc[i][j] = fmaf(a0[i], b0[j], acc[i][j]);
        }
    }

    const float g = gamma_ptr[0];
    #pragma unroll
    for (int i2 = 0; i2 < 8; ++i2) {
        int r = ty*8 + i2;
        int no = (mode == 0) ? r*Ww + L : L*Ww + r;
        size_t off = ((size_t)b*HW + no)*Cc + c0 + tx*8;
        float* dp = dest + off;
        if (mode == 0) {
            const float* bp = base + off;
            float4 b0 = ((const float4*)bp)[0], b1 = ((const float4*)bp)[1];
            float4 o0, o1;
            o0.x = b0.x + g*acc[i2][0]; o0.y = b0.y + g*acc[i2][1];
            o0.z = b0.z + g*acc[i2][2]; o0.w = b0.w + g*acc[i2][3];
            o1.x = b1.x + g*acc[i2][4]; o1.y = b1.y + g*acc[i2][5];
            o1.z = b1.z + g*acc[i2][6]; o1.w = b1.w + g*acc[i2][7];
            ((float4*)dp)[0] = o0; ((float4*)dp)[1] = o1;
        } else {
            float4 d0 = ((float4*)dp)[0], d1 = ((float4*)dp)[1];
            d0.x += g*acc[i2][0]; d0.y += g*acc[i2][1];
            d0.z += g*acc[i2][2]; d0.w += g*acc[i2][3];
            d1.x += g*acc[i2][4]; d1.y += g*acc[i2][5];
            d1.z += g*acc[i2][6]; d1.w += g*acc[i2][7];
            ((float4*)dp)[0] = d0; ((float4*)dp)[1] = d1;
        }
    }
}

extern "C" void kernel_launch(void* const* d_in, const int* in_sizes, int n_in,
                              void* d_out, int out_size, void* d_ws, size_t ws_size,
                              hipStream_t stream)
{
    const float* x     = (const float*)d_in[0];
    const float* wq    = (const float*)d_in[1];
    const float* bq    = (const float*)d_in[2];
    const float* wk    = (const float*)d_in[3];
    const float* bk    = (const float*)d_in[4];
    const float* wv    = (const float*)d_in[5];
    const float* bv    = (const float*)d_in[6];
    const float* gamma = (const float*)d_in[7];
    const float* wq1   = (const float*)d_in[8];
    const float* bq1   = (const float*)d_in[9];
    const float* wk1   = (const float*)d_in[10];
    const float* bk1   = (const float*)d_in[11];
    const float* wv1   = (const float*)d_in[12];
    const float* bv1   = (const float*)d_in[13];
    const float* gamma1= (const float*)d_in[14];
    const float* w7    = (const float*)d_in[15];
    const float* b7    = (const float*)d_in[16];
    const float* w5    = (const float*)d_in[17];
    const float* b5    = (const float*)d_in[18];
    const float* w3    = (const float*)d_in[19];
    const float* b3    = (const float*)d_in[20];
    float* outp = (float*)d_out;

    // workspace layout (floats): q(2M) k(2M) v(16.8M) e(8.4M) wt(43K) ~= 118 MB
    // block-1 intermediate `ob` lives in d_out (fully overwritten before any read).
    float* ws = (float*)d_ws;
    float* qb = ws;
    float* kb = qb + (size_t)2*HW*CQ;
    float* vb = kb + (size_t)2*HW*CQ;
    float* eb = vb + (size_t)2*HW*Cc;
    float* wt = eb + (size_t)2*2*128*16384;
    float* ob = outp;

    prep_weights<<<dim3(2), dim3(256), 0, stream>>>(w7,b7,w5,b5,w3,b3, wt);

    // ---- criss-cross block 1 (input x) ----
    qkv_gemm  <<<dim3(128,10,2), dim3(256), 0, stream>>>(x, wq,bq,wk,bk,wv,bv, qb,kb,vb);
    cc_scores <<<dim3(128,2,2),  dim3(256), 0, stream>>>(qb, kb, eb);
    cc_softmax<<<dim3(128,2,2),  dim3(128), 0, stream>>>(eb);
    cnn_resid <<<dim3(8192,1,2), dim3(256), 0, stream>>>(x, wt, ob);       // ob = x + cnn_feat1
    cc_agg    <<<dim3(128,4,2),  dim3(256), 0, stream>>>(eb, vb, ob, ob, gamma, 0); // ob += g*col
    cc_agg    <<<dim3(128,4,2),  dim3(256), 0, stream>>>(eb, vb, ob, ob, gamma, 1); // ob += g*row

    // ---- criss-cross block 2 (input ob, residual ob, output d_out) ----
    qkv_gemm  <<<dim3(128,10,2), dim3(256), 0, stream>>>(ob, wq1,bq1,wk1,bk1,wv1,bv1, qb,kb,vb);
    cc_scores <<<dim3(128,2,2),  dim3(256), 0, stream>>>(qb, kb, eb);
    cc_softmax<<<dim3(128,2,2),  dim3(128), 0, stream>>>(eb);
    cc_agg    <<<dim3(128,4,2),  dim3(256), 0, stream>>>(eb, vb, ob, outp, gamma1, 0); // out = ob + g1*col
    cc_agg    <<<dim3(128,4,2),  dim3(256), 0, stream>>>(eb, vb, ob, outp, gamma1, 1); // out += g1*row
}

// Round 4
// 692.233 us; speedup vs baseline: 1.9575x; 1.9575x over previous
//
#include <hip/hip_runtime.h>
#include <hip/hip_bf16.h>

#define Hh 128
#define Ww 128
#define HW 16384
#define Cc 512
#define CQ 64

typedef __attribute__((ext_vector_type(8))) short short8;
typedef __attribute__((ext_vector_type(4))) float f32x4;

// ---------------- prep: combined dwconv weights (7x7 taps with 5x5+3x3 folded in) ----------------
// wtc rows: 0..48 = combined taps (di*7+dj), 49 = b7+b5+b3
__global__ void prep_weights(const float* __restrict__ w7, const float* __restrict__ b7,
                             const float* __restrict__ w5, const float* __restrict__ b5,
                             const float* __restrict__ w3, const float* __restrict__ b3,
                             float* __restrict__ wtc)
{
    int c = blockIdx.x * 256 + threadIdx.x;
    if (c >= Cc) return;
    for (int di = 0; di < 7; ++di)
        for (int dj = 0; dj < 7; ++dj) {
            float w = w7[c*49 + di*7 + dj];
            if (di >= 1 && di <= 5 && dj >= 1 && dj <= 5) w += w5[c*25 + (di-1)*5 + (dj-1)];
            if (di >= 2 && di <= 4 && dj >= 2 && dj <= 4) w += w3[c*9  + (di-2)*3 + (dj-2)];
            wtc[(di*7+dj)*Cc + c] = w;
        }
    wtc[49*Cc + c] = b7[c] + b5[c] + b3[c];
}

// ---------------- convert fp32 -> bf16 (stream) ----------------
__global__ void to_bf16(const float* __restrict__ src, unsigned short* __restrict__ dst, int n)
{
    int stride = gridDim.x * 256 * 4;
    for (int i = (blockIdx.x*256 + threadIdx.x)*4; i < n; i += stride) {
        float4 v = *(const float4*)&src[i];
        __hip_bfloat16 h0 = __float2bfloat16(v.x);
        __hip_bfloat16 h1 = __float2bfloat16(v.y);
        __hip_bfloat16 h2 = __float2bfloat16(v.z);
        __hip_bfloat16 h3 = __float2bfloat16(v.w);
        ushort4 o;
        o.x = *(unsigned short*)&h0; o.y = *(unsigned short*)&h1;
        o.z = *(unsigned short*)&h2; o.w = *(unsigned short*)&h3;
        *(ushort4*)&dst[i] = o;
    }
}

// ---------------- convert QKV weights to one bf16 matrix [640][512]: rows 0-63 wq, 64-127 wk, 128-639 wv ----
__global__ void prep_wbf(const float* __restrict__ wq, const float* __restrict__ wk,
                         const float* __restrict__ wv, unsigned short* __restrict__ wb)
{
    int e = (blockIdx.x*256 + threadIdx.x)*4;   // 640*512 = 327680 elems, grid 320
    if (e >= 640*Cc) return;
    int row = e >> 9, col = e & 511;
    const float* s;
    if (row < 64)       s = wq + (size_t)row*Cc;
    else if (row < 128) s = wk + (size_t)(row-64)*Cc;
    else                s = wv + (size_t)(row-128)*Cc;
    float4 v = *(const float4*)&s[col];
    __hip_bfloat16 h0 = __float2bfloat16(v.x);
    __hip_bfloat16 h1 = __float2bfloat16(v.y);
    __hip_bfloat16 h2 = __float2bfloat16(v.z);
    __hip_bfloat16 h3 = __float2bfloat16(v.w);
    ushort4 o;
    o.x = *(unsigned short*)&h0; o.y = *(unsigned short*)&h1;
    o.z = *(unsigned short*)&h2; o.w = *(unsigned short*)&h3;
    *(ushort4*)&wb[e] = o;
}

// ---------------- fused QKV GEMM, bf16 MFMA ----------------
// xb: bf16 [b][HW][512]; wb: bf16 [640][512]. Outputs fp32 q,k:(b,HW,64) v:(b,HW,512) +bias.
// Tile: BM=128, BN=64, BK=32. 4 waves in 2x2; wave tile 64(M)x32(N) = 4x2 frags of 16x16.
__global__ __launch_bounds__(256) void qkv_gemm_mfma(
    const short* __restrict__ xb, const short* __restrict__ wb,
    const float* __restrict__ bq, const float* __restrict__ bk, const float* __restrict__ bv,
    float* __restrict__ qo, float* __restrict__ ko, float* __restrict__ vo)
{
    const int b  = blockIdx.z;
    const int m0 = blockIdx.x * 128;
    const int n0 = blockIdx.y * 64;            // global output row in wb: 0..639

    __shared__ short Al[128][40];              // [m][k] bf16, pad 32->40 (80B row: 2-way banks)
    __shared__ short Bl[64][40];               // [n][k] bf16

    const int tid  = threadIdx.x;
    const int wid  = tid >> 6;
    const int lane = tid & 63;
    const int wm = wid >> 1, wn = wid & 1;     // 2x2 wave grid
    const int lr = lane & 15, lg = lane >> 4;

    const short* Ag = xb + (size_t)b*HW*Cc + (size_t)m0*Cc;
    const short* Bg = wb + (size_t)n0*Cc;

    f32x4 acc[4][2];
    #pragma unroll
    for (int i = 0; i < 4; ++i)
        #pragma unroll
        for (int j = 0; j < 2; ++j) acc[i][j] = (f32x4){0.f,0.f,0.f,0.f};

    for (int k0 = 0; k0 < Cc; k0 += 32) {
        __syncthreads();
        #pragma unroll
        for (int r = 0; r < 2; ++r) {          // A: 128 rows x 4 chunks of 8 bf16
            int idx = tid + r*256;
            int row = idx >> 2, ch = idx & 3;
            *(short8*)&Al[row][ch*8] = *(const short8*)&Ag[(size_t)row*Cc + k0 + ch*8];
        }
        {                                       // B: 64 rows x 4 chunks
            int row = tid >> 2, ch = tid & 3;
            *(short8*)&Bl[row][ch*8] = *(const short8*)&Bg[(size_t)row*Cc + k0 + ch*8];
        }
        __syncthreads();

        short8 af[4], bf[2];
        #pragma unroll
        for (int mi = 0; mi < 4; ++mi) af[mi] = *(const short8*)&Al[wm*64 + mi*16 + lr][lg*8];
        #pragma unroll
        for (int ni = 0; ni < 2; ++ni) bf[ni] = *(const short8*)&Bl[wn*32 + ni*16 + lr][lg*8];
        #pragma unroll
        for (int mi = 0; mi < 4; ++mi)
            #pragma unroll
            for (int ni = 0; ni < 2; ++ni)
                acc[mi][ni] = __builtin_amdgcn_mfma_f32_16x16x32_bf16(af[mi], bf[ni], acc[mi][ni], 0, 0, 0);
    }

    // epilogue: pick output buffer
    const float* bias; float* Out; int oc, nr;
    if (n0 < 64)       { bias = bq; Out = qo + (size_t)b*HW*CQ; oc = CQ; nr = 0; }
    else if (n0 < 128) { bias = bk; Out = ko + (size_t)b*HW*CQ; oc = CQ; nr = n0 - 64; }
    else               { bias = bv; Out = vo + (size_t)b*HW*Cc; oc = Cc; nr = n0 - 128; }

    #pragma unroll
    for (int mi = 0; mi < 4; ++mi)
        #pragma unroll
        for (int ni = 0; ni < 2; ++ni) {
            int col = nr + wn*32 + ni*16 + lr;
            float bv_ = bias[col];
            #pragma unroll
            for (int r = 0; r < 4; ++r) {
                int m = m0 + wm*64 + mi*16 + lg*4 + r;
                Out[(size_t)m*oc + col] = acc[mi][ni][r] + bv_;
            }
        }
}

// ---------------- criss-cross scores (fp32) ----------------
// e layout: e[((b*2+mode)*128 + L)*16384 + r*128 + k]
__global__ __launch_bounds__(256) void cc_scores(
    const float* __restrict__ qi, const float* __restrict__ ki, float* __restrict__ e)
{
    const int L = blockIdx.x;
    const int mode = blockIdx.y;
    const int b = blockIdx.z;
    const float* qb = qi + (size_t)b*HW*CQ;
    const float* kb = ki + (size_t)b*HW*CQ;
    float* eb = e + ((size_t)((b*2+mode)*128 + L)) * 16384;

    __shared__ float Qs[16][132];
    __shared__ float Ks[16][132];
    const int tid = threadIdx.x;
    const int tx = tid & 15, ty = tid >> 4;

    float acc[8][8];
    #pragma unroll
    for (int i = 0; i < 8; ++i)
        #pragma unroll
        for (int j = 0; j < 8; ++j) acc[i][j] = 0.f;

    for (int c0 = 0; c0 < CQ; c0 += 16) {
        __syncthreads();
        #pragma unroll
        for (int r = 0; r < 2; ++r) {
            int t = tid + r*256;
            int row = t >> 2;
            int c4  = (t & 3) * 4;
            int n = (mode == 0) ? row*Ww + L : L*Ww + row;
            float4 a = *(const float4*)&qb[(size_t)n*CQ + c0 + c4];
            Qs[c4+0][row] = a.x; Qs[c4+1][row] = a.y; Qs[c4+2][row] = a.z; Qs[c4+3][row] = a.w;
            float4 kk4 = *(const float4*)&kb[(size_t)n*CQ + c0 + c4];
            Ks[c4+0][row] = kk4.x; Ks[c4+1][row] = kk4.y; Ks[c4+2][row] = kk4.z; Ks[c4+3][row] = kk4.w;
        }
        __syncthreads();
        #pragma unroll
        for (int cc = 0; cc < 16; ++cc) {
            float a0[8], b0[8];
            #pragma unroll
            for (int i = 0; i < 8; ++i) a0[i] = Qs[cc][ty*8+i];
            #pragma unroll
            for (int j = 0; j < 8; ++j) b0[j] = Ks[cc][tx*8+j];
            #pragma unroll
            for (int i = 0; i < 8; ++i)
                #pragma unroll
                for (int j = 0; j < 8; ++j) acc[i][j] = fmaf(a0[i], b0[j], acc[i][j]);
        }
    }

    #pragma unroll
    for (int i = 0; i < 8; ++i) {
        int r = ty*8 + i;
        float4 o0, o1;
        o0.x = acc[i][0]; o0.y = acc[i][1]; o0.z = acc[i][2]; o0.w = acc[i][3];
        o1.x = acc[i][4]; o1.y = acc[i][5]; o1.z = acc[i][6]; o1.w = acc[i][7];
        *(float4*)&eb[r*128 + tx*8 + 0] = o0;
        *(float4*)&eb[r*128 + tx*8 + 4] = o1;
    }
}

// ---------------- softmax over axis i (axis=1 of att) ----------------
__global__ __launch_bounds__(128) void cc_softmax(float* __restrict__ e)
{
    const int L = blockIdx.x, mode = blockIdx.y, b = blockIdx.z;
    const int k = threadIdx.x;
    float* base; int stride;
    if (mode == 0) { base = e + ((size_t)(b*2)*128 + L)*16384 + k;          stride = 128;   }
    else           { base = e + ((size_t)(b*2+1)*128)*16384 + L*128 + k;    stride = 16384; }
    float m = -1e30f, s = 0.f;
    #pragma unroll 8
    for (int i = 0; i < 128; ++i) {
        float val = base[i*stride];
        float mn = fmaxf(m, val);
        s = s*__expf(m - mn) + __expf(val - mn);
        m = mn;
    }
    float inv = 1.f / s;
    #pragma unroll 8
    for (int i = 0; i < 128; ++i) {
        float val = base[i*stride];
        base[i*stride] = __expf(val - m) * inv;
    }
}

// ---------------- fused depthwise conv (combined taps) + residual, 8-wide strips ----------------
// out[b,n,c] = x[b,n,c] + conv(x) + biases ; thread owns 8 consecutive j positions, 4 channels
__global__ __launch_bounds__(256) void cnn_resid(
    const float* __restrict__ x, const float* __restrict__ wtc, float* __restrict__ out)
{
    const int tid = threadIdx.x;
    const int c0  = (tid & 127) * 4;
    const int s   = tid >> 7;
    const int g   = blockIdx.x * 2 + s;        // strip id: 128 rows x 16 strips
    const int b   = blockIdx.z;
    const int i   = g >> 4;
    const int j0  = (g & 15) * 8;
    const float* xb = x + (size_t)b*HW*Cc;

    float4 acc[8];
    {
        float4 bias = *(const float4*)&wtc[49*Cc + c0];
        #pragma unroll
        for (int t = 0; t < 8; ++t) {
            float4 xv = *(const float4*)&xb[(size_t)(i*Ww + j0 + t)*Cc + c0];
            acc[t].x = bias.x + xv.x; acc[t].y = bias.y + xv.y;
            acc[t].z = bias.z + xv.z; acc[t].w = bias.w + xv.w;
        }
    }

    #pragma unroll
    for (int di = 0; di < 7; ++di) {
        int ii = i + di - 3;
        if (ii >= 0 && ii < Hh) {
            float4 xv[14];
            #pragma unroll
            for (int u = 0; u < 14; ++u) {
                int jj = j0 - 3 + u;
                if (jj >= 0 && jj < Ww) xv[u] = *(const float4*)&xb[(size_t)(ii*Ww + jj)*Cc + c0];
                else { xv[u].x = 0.f; xv[u].y = 0.f; xv[u].z = 0.f; xv[u].w = 0.f; }
            }
            #pragma unroll
            for (int dj = 0; dj < 7; ++dj) {
                float4 w = *(const float4*)&wtc[(di*7 + dj)*Cc + c0];
                #pragma unroll
                for (int t = 0; t < 8; ++t) {
                    acc[t].x = fmaf(xv[t+dj].x, w.x, acc[t].x);
                    acc[t].y = fmaf(xv[t+dj].y, w.y, acc[t].y);
                    acc[t].z = fmaf(xv[t+dj].z, w.z, acc[t].z);
                    acc[t].w = fmaf(xv[t+dj].w, w.w, acc[t].w);
                }
            }
        }
    }

    #pragma unroll
    for (int t = 0; t < 8; ++t)
        *(float4*)&out[((size_t)b*HW + i*Ww + j0 + t)*Cc + c0] = acc[t];
}

// ---------------- aggregation: dest = base + gamma * (att @ V) (fp32) ----------------
__global__ __launch_bounds__(256) void cc_agg(
    const float* __restrict__ att, const float* __restrict__ v,
    const float* __restrict__ base, float* __restrict__ dest,
    const float* __restrict__ gamma_ptr, const int mode)
{
    const int L  = blockIdx.x;
    const int c0 = blockIdx.y * 128;
    const int b  = blockIdx.z;
    const float* A  = att + ((size_t)((b*2+mode)*128 + L)) * 16384;  // [r][k] 128x128
    const float* vb = v + (size_t)b*HW*Cc;

    __shared__ float As[16][132];
    __shared__ float Bs[16][132];
    const int tid = threadIdx.x;
    const int tx = tid & 15, ty = tid >> 4;

    float acc[8][8];
    #pragma unroll
    for (int i = 0; i < 8; ++i)
        #pragma unroll
        for (int j = 0; j < 8; ++j) acc[i][j] = 0.f;

    for (int k0 = 0; k0 < 128; k0 += 16) {
        __syncthreads();
        #pragma unroll
        for (int r = 0; r < 2; ++r) {
            int t = tid + r*256;
            int row = t >> 2;
            int c4  = (t & 3) * 4;
            float4 a = *(const float4*)&A[row*128 + k0 + c4];
            As[c4+0][row] = a.x; As[c4+1][row] = a.y; As[c4+2][row] = a.z; As[c4+3][row] = a.w;

            int rowk = (tid >> 5) + r*8;
            int cc   = (tid & 31) * 4;
            int nv = (mode == 0) ? (k0+rowk)*Ww + L : L*Ww + (k0+rowk);
            float4 vv = *(const float4*)&vb[(size_t)nv*Cc + c0 + cc];
            *(float4*)&Bs[rowk][cc] = vv;
        }
        __syncthreads();
        #pragma unroll
        for (int kk = 0; kk < 16; ++kk) {
            float a0[8], b0[8];
            #pragma unroll
            for (int i = 0; i < 8; ++i) a0[i] = As[kk][ty*8+i];
            #pragma unroll
            for (int j = 0; j < 8; ++j) b0[j] = Bs[kk][tx*8+j];
            #pragma unroll
            for (int i = 0; i < 8; ++i)
                #pragma unroll
                for (int j = 0; j < 8; ++j) acc[i][j] = fmaf(a0[i], b0[j], acc[i][j]);
        }
    }

    const float g = gamma_ptr[0];
    #pragma unroll
    for (int i2 = 0; i2 < 8; ++i2) {
        int r = ty*8 + i2;
        int no = (mode == 0) ? r*Ww + L : L*Ww + r;
        size_t off = ((size_t)b*HW + no)*Cc + c0 + tx*8;
        float* dp = dest + off;
        if (mode == 0) {
            const float* bp = base + off;
            float4 b0 = ((const float4*)bp)[0], b1 = ((const float4*)bp)[1];
            float4 o0, o1;
            o0.x = b0.x + g*acc[i2][0]; o0.y = b0.y + g*acc[i2][1];
            o0.z = b0.z + g*acc[i2][2]; o0.w = b0.w + g*acc[i2][3];
            o1.x = b1.x + g*acc[i2][4]; o1.y = b1.y + g*acc[i2][5];
            o1.z = b1.z + g*acc[i2][6]; o1.w = b1.w + g*acc[i2][7];
            ((float4*)dp)[0] = o0; ((float4*)dp)[1] = o1;
        } else {
            float4 d0 = ((float4*)dp)[0], d1 = ((float4*)dp)[1];
            d0.x += g*acc[i2][0]; d0.y += g*acc[i2][1];
            d0.z += g*acc[i2][2]; d0.w += g*acc[i2][3];
            d1.x += g*acc[i2][4]; d1.y += g*acc[i2][5];
            d1.z += g*acc[i2][6]; d1.w += g*acc[i2][7];
            ((float4*)dp)[0] = d0; ((float4*)dp)[1] = d1;
        }
    }
}

extern "C" void kernel_launch(void* const* d_in, const int* in_sizes, int n_in,
                              void* d_out, int out_size, void* d_ws, size_t ws_size,
                              hipStream_t stream)
{
    const float* x     = (const float*)d_in[0];
    const float* wq    = (const float*)d_in[1];
    const float* bq    = (const float*)d_in[2];
    const float* wk    = (const float*)d_in[3];
    const float* bk    = (const float*)d_in[4];
    const float* wv    = (const float*)d_in[5];
    const float* bv    = (const float*)d_in[6];
    const float* gamma = (const float*)d_in[7];
    const float* wq1   = (const float*)d_in[8];
    const float* bq1   = (const float*)d_in[9];
    const float* wk1   = (const float*)d_in[10];
    const float* bk1   = (const float*)d_in[11];
    const float* wv1   = (const float*)d_in[12];
    const float* bv1   = (const float*)d_in[13];
    const float* gamma1= (const float*)d_in[14];
    const float* w7    = (const float*)d_in[15];
    const float* b7    = (const float*)d_in[16];
    const float* w5    = (const float*)d_in[17];
    const float* b5    = (const float*)d_in[18];
    const float* w3    = (const float*)d_in[19];
    const float* b3    = (const float*)d_in[20];
    float* outp = (float*)d_out;

    // workspace layout: fp32 q(2M) k(2M) v(16.8M) e(8.4M) wtc(25.6K) + bf16 xbf(16.8M us) wb0/wb1(327K us each)
    float* ws = (float*)d_ws;
    float* qb  = ws;
    float* kb  = qb + (size_t)2*HW*CQ;
    float* vb  = kb + (size_t)2*HW*CQ;
    float* eb  = vb + (size_t)2*HW*Cc;
    float* wtc = eb + (size_t)2*2*128*16384;
    unsigned short* xbf = (unsigned short*)(wtc + 50*Cc);
    unsigned short* wb0 = xbf + (size_t)2*HW*Cc;
    unsigned short* wb1 = wb0 + (size_t)640*Cc;
    float* ob = outp;   // block-1 intermediate lives in d_out

    prep_weights<<<dim3(2), dim3(256), 0, stream>>>(w7,b7,w5,b5,w3,b3, wtc);
    prep_wbf    <<<dim3(320), dim3(256), 0, stream>>>(wq, wk, wv, wb0);
    prep_wbf    <<<dim3(320), dim3(256), 0, stream>>>(wq1, wk1, wv1, wb1);
    to_bf16     <<<dim3(2048), dim3(256), 0, stream>>>(x, xbf, 2*HW*Cc);

    // ---- criss-cross block 1 (input x) ----
    qkv_gemm_mfma<<<dim3(128,10,2), dim3(256), 0, stream>>>((const short*)xbf, (const short*)wb0,
                                                            bq,bk,bv, qb,kb,vb);
    cc_scores <<<dim3(128,2,2),  dim3(256), 0, stream>>>(qb, kb, eb);
    cc_softmax<<<dim3(128,2,2),  dim3(128), 0, stream>>>(eb);
    cnn_resid <<<dim3(1024,1,2), dim3(256), 0, stream>>>(x, wtc, ob);      // ob = x + cnn_feat1
    cc_agg    <<<dim3(128,4,2),  dim3(256), 0, stream>>>(eb, vb, ob, ob, gamma, 0);
    cc_agg    <<<dim3(128,4,2),  dim3(256), 0, stream>>>(eb, vb, ob, ob, gamma, 1);

    // ---- criss-cross block 2 (input ob, residual ob, output d_out) ----
    to_bf16     <<<dim3(2048), dim3(256), 0, stream>>>(ob, xbf, 2*HW*Cc);
    qkv_gemm_mfma<<<dim3(128,10,2), dim3(256), 0, stream>>>((const short*)xbf, (const short*)wb1,
                                                            bq1,bk1,bv1, qb,kb,vb);
    cc_scores <<<dim3(128,2,2),  dim3(256), 0, stream>>>(qb, kb, eb);
    cc_softmax<<<dim3(128,2,2),  dim3(128), 0, stream>>>(eb);
    cc_agg    <<<dim3(128,4,2),  dim3(256), 0, stream>>>(eb, vb, ob, outp, gamma1, 0);
    cc_agg    <<<dim3(128,4,2),  dim3(256), 0, stream>>>(eb, vb, ob, outp, gamma1, 1);
}

// Round 5
// 672.094 us; speedup vs baseline: 2.0162x; 1.0300x over previous
//
#include <hip/hip_runtime.h>
#include <hip/hip_bf16.h>

#define Hh 128
#define Ww 128
#define HW 16384
#define Cc 512
#define CQ 64

typedef __attribute__((ext_vector_type(8))) short short8;
typedef __attribute__((ext_vector_type(4))) float f32x4;

static __device__ __forceinline__ unsigned short f2bf(float f) {
    __hip_bfloat16 h = __float2bfloat16(f);
    return *(unsigned short*)&h;
}

// ---------------- prep: combined dwconv weights (7x7 taps with 5x5+3x3 folded in) ----------------
__global__ void prep_weights(const float* __restrict__ w7, const float* __restrict__ b7,
                             const float* __restrict__ w5, const float* __restrict__ b5,
                             const float* __restrict__ w3, const float* __restrict__ b3,
                             float* __restrict__ wtc)
{
    int c = blockIdx.x * 256 + threadIdx.x;
    if (c >= Cc) return;
    for (int di = 0; di < 7; ++di)
        for (int dj = 0; dj < 7; ++dj) {
            float w = w7[c*49 + di*7 + dj];
            if (di >= 1 && di <= 5 && dj >= 1 && dj <= 5) w += w5[c*25 + (di-1)*5 + (dj-1)];
            if (di >= 2 && di <= 4 && dj >= 2 && dj <= 4) w += w3[c*9  + (di-2)*3 + (dj-2)];
            wtc[(di*7+dj)*Cc + c] = w;
        }
    wtc[49*Cc + c] = b7[c] + b5[c] + b3[c];
}

// ---------------- convert fp32 -> bf16 (stream) ----------------
__global__ void to_bf16(const float* __restrict__ src, unsigned short* __restrict__ dst, int n)
{
    int stride = gridDim.x * 256 * 4;
    for (int i = (blockIdx.x*256 + threadIdx.x)*4; i < n; i += stride) {
        float4 v = *(const float4*)&src[i];
        ushort4 o;
        o.x = f2bf(v.x); o.y = f2bf(v.y); o.z = f2bf(v.z); o.w = f2bf(v.w);
        *(ushort4*)&dst[i] = o;
    }
}

// ---------------- QKV weights -> one bf16 matrix [640][512] ----------------
__global__ void prep_wbf(const float* __restrict__ wq, const float* __restrict__ wk,
                         const float* __restrict__ wv, unsigned short* __restrict__ wb)
{
    int e = (blockIdx.x*256 + threadIdx.x)*4;
    if (e >= 640*Cc) return;
    int row = e >> 9, col = e & 511;
    const float* s;
    if (row < 64)       s = wq + (size_t)row*Cc;
    else if (row < 128) s = wk + (size_t)(row-64)*Cc;
    else                s = wv + (size_t)(row-128)*Cc;
    float4 v = *(const float4*)&s[col];
    ushort4 o;
    o.x = f2bf(v.x); o.y = f2bf(v.y); o.z = f2bf(v.z); o.w = f2bf(v.w);
    *(ushort4*)&wb[e] = o;
}

// ---------------- fused QKV GEMM, bf16 MFMA; Q,K fp32 out; V bf16 out ----------------
__global__ __launch_bounds__(256) void qkv_gemm_mfma(
    const short* __restrict__ xb, const short* __restrict__ wb,
    const float* __restrict__ bq, const float* __restrict__ bk, const float* __restrict__ bv,
    float* __restrict__ qo, float* __restrict__ ko, unsigned short* __restrict__ vbf)
{
    const int b  = blockIdx.z;
    const int m0 = blockIdx.x * 128;
    const int n0 = blockIdx.y * 64;

    __shared__ short Al[128][40];
    __shared__ short Bl[64][40];

    const int tid  = threadIdx.x;
    const int wid  = tid >> 6;
    const int lane = tid & 63;
    const int wm = wid >> 1, wn = wid & 1;
    const int lr = lane & 15, lg = lane >> 4;

    const short* Ag = xb + (size_t)b*HW*Cc + (size_t)m0*Cc;
    const short* Bg = wb + (size_t)n0*Cc;

    f32x4 acc[4][2];
    #pragma unroll
    for (int i = 0; i < 4; ++i)
        #pragma unroll
        for (int j = 0; j < 2; ++j) acc[i][j] = (f32x4){0.f,0.f,0.f,0.f};

    for (int k0 = 0; k0 < Cc; k0 += 32) {
        __syncthreads();
        #pragma unroll
        for (int r = 0; r < 2; ++r) {
            int idx = tid + r*256;
            int row = idx >> 2, ch = idx & 3;
            *(short8*)&Al[row][ch*8] = *(const short8*)&Ag[(size_t)row*Cc + k0 + ch*8];
        }
        {
            int row = tid >> 2, ch = tid & 3;
            *(short8*)&Bl[row][ch*8] = *(const short8*)&Bg[(size_t)row*Cc + k0 + ch*8];
        }
        __syncthreads();

        short8 af[4], bf[2];
        #pragma unroll
        for (int mi = 0; mi < 4; ++mi) af[mi] = *(const short8*)&Al[wm*64 + mi*16 + lr][lg*8];
        #pragma unroll
        for (int ni = 0; ni < 2; ++ni) bf[ni] = *(const short8*)&Bl[wn*32 + ni*16 + lr][lg*8];
        #pragma unroll
        for (int mi = 0; mi < 4; ++mi)
            #pragma unroll
            for (int ni = 0; ni < 2; ++ni)
                acc[mi][ni] = __builtin_amdgcn_mfma_f32_16x16x32_bf16(af[mi], bf[ni], acc[mi][ni], 0, 0, 0);
    }

    if (n0 < 128) {   // Q or K -> fp32
        const float* bias; float* Out; int nr;
        if (n0 < 64) { bias = bq; Out = qo + (size_t)b*HW*CQ; nr = 0; }
        else         { bias = bk; Out = ko + (size_t)b*HW*CQ; nr = 0; }
        #pragma unroll
        for (int mi = 0; mi < 4; ++mi)
            #pragma unroll
            for (int ni = 0; ni < 2; ++ni) {
                int col = nr + wn*32 + ni*16 + lr;
                float bv_ = bias[col];
                #pragma unroll
                for (int r = 0; r < 4; ++r) {
                    int m = m0 + wm*64 + mi*16 + lg*4 + r;
                    Out[(size_t)m*CQ + col] = acc[mi][ni][r] + bv_;
                }
            }
    } else {          // V -> bf16
        int nr = n0 - 128;
        unsigned short* Out = vbf + (size_t)b*HW*Cc;
        #pragma unroll
        for (int mi = 0; mi < 4; ++mi)
            #pragma unroll
            for (int ni = 0; ni < 2; ++ni) {
                int col = nr + wn*32 + ni*16 + lr;
                float bv_ = bv[col];
                #pragma unroll
                for (int r = 0; r < 4; ++r) {
                    int m = m0 + wm*64 + mi*16 + lg*4 + r;
                    Out[(size_t)m*Cc + col] = f2bf(acc[mi][ni][r] + bv_);
                }
            }
    }
}

// ---------------- V transposes: vcol[b][j][c][k]=V[k*128+j][c], vrow[b][i][c][k]=V[i*128+k][c] ----
// In-register 8x8 transpose; coalesced both sides.
__global__ __launch_bounds__(256) void vtrans(
    const unsigned short* __restrict__ vbf,
    unsigned short* __restrict__ vcol, unsigned short* __restrict__ vrow)
{
    const int L  = blockIdx.x;
    const int ct = blockIdx.y;
    const int bz = blockIdx.z;
    const int b = bz >> 1, mode = bz & 1;
    const int tid = threadIdx.x;
    const int lk = tid & 15;
    const int lc = tid >> 4;
    const int c0 = ct*128 + lc*8;
    const unsigned short* src = vbf + (size_t)b*HW*Cc;

    short8 in[8];
    #pragma unroll
    for (int u = 0; u < 8; ++u) {
        int k = lk*8 + u;
        int row = mode ? L*128 + k : k*128 + L;
        in[u] = *(const short8*)&src[(size_t)row*Cc + c0];
    }
    unsigned short* dst = (mode ? vrow : vcol) + (((size_t)(b*128 + L))*Cc + c0)*128 + lk*8;
    #pragma unroll
    for (int t = 0; t < 8; ++t) {
        short8 o;
        #pragma unroll
        for (int u = 0; u < 8; ++u) o[u] = in[u][t];
        *(short8*)&dst[(size_t)t*128] = o;
    }
}

// ---------------- criss-cross scores (fp32) ----------------
__global__ __launch_bounds__(256) void cc_scores(
    const float* __restrict__ qi, const float* __restrict__ ki, float* __restrict__ e)
{
    const int L = blockIdx.x;
    const int mode = blockIdx.y;
    const int b = blockIdx.z;
    const float* qb = qi + (size_t)b*HW*CQ;
    const float* kb = ki + (size_t)b*HW*CQ;
    float* eb = e + ((size_t)((b*2+mode)*128 + L)) * 16384;

    __shared__ float Qs[16][132];
    __shared__ float Ks[16][132];
    const int tid = threadIdx.x;
    const int tx = tid & 15, ty = tid >> 4;

    float acc[8][8];
    #pragma unroll
    for (int i = 0; i < 8; ++i)
        #pragma unroll
        for (int j = 0; j < 8; ++j) acc[i][j] = 0.f;

    for (int c0 = 0; c0 < CQ; c0 += 16) {
        __syncthreads();
        #pragma unroll
        for (int r = 0; r < 2; ++r) {
            int t = tid + r*256;
            int row = t >> 2;
            int c4  = (t & 3) * 4;
            int n = (mode == 0) ? row*Ww + L : L*Ww + row;
            float4 a = *(const float4*)&qb[(size_t)n*CQ + c0 + c4];
            Qs[c4+0][row] = a.x; Qs[c4+1][row] = a.y; Qs[c4+2][row] = a.z; Qs[c4+3][row] = a.w;
            float4 kk4 = *(const float4*)&kb[(size_t)n*CQ + c0 + c4];
            Ks[c4+0][row] = kk4.x; Ks[c4+1][row] = kk4.y; Ks[c4+2][row] = kk4.z; Ks[c4+3][row] = kk4.w;
        }
        __syncthreads();
        #pragma unroll
        for (int cc = 0; cc < 16; ++cc) {
            float a0[8], b0[8];
            #pragma unroll
            for (int i = 0; i < 8; ++i) a0[i] = Qs[cc][ty*8+i];
            #pragma unroll
            for (int j = 0; j < 8; ++j) b0[j] = Ks[cc][tx*8+j];
            #pragma unroll
            for (int i = 0; i < 8; ++i)
                #pragma unroll
                for (int j = 0; j < 8; ++j) acc[i][j] = fmaf(a0[i], b0[j], acc[i][j]);
        }
    }

    #pragma unroll
    for (int i = 0; i < 8; ++i) {
        int r = ty*8 + i;
        float4 o0, o1;
        o0.x = acc[i][0]; o0.y = acc[i][1]; o0.z = acc[i][2]; o0.w = acc[i][3];
        o1.x = acc[i][4]; o1.y = acc[i][5]; o1.z = acc[i][6]; o1.w = acc[i][7];
        *(float4*)&eb[r*128 + tx*8 + 0] = o0;
        *(float4*)&eb[r*128 + tx*8 + 4] = o1;
    }
}

// ---------------- softmax over axis i; fp32 in -> bf16 att out ----------------
__global__ __launch_bounds__(128) void cc_softmax(const float* __restrict__ e,
                                                  unsigned short* __restrict__ attb)
{
    const int L = blockIdx.x, mode = blockIdx.y, b = blockIdx.z;
    const int k = threadIdx.x;
    size_t off; int stride;
    if (mode == 0) { off = ((size_t)(b*2)*128 + L)*16384 + k;        stride = 128;   }
    else           { off = ((size_t)(b*2+1)*128)*16384 + L*128 + k;  stride = 16384; }
    const float* base = e + off;
    unsigned short* ob = attb + off;
    float m = -1e30f, s = 0.f;
    #pragma unroll 8
    for (int i = 0; i < 128; ++i) {
        float val = base[i*stride];
        float mn = fmaxf(m, val);
        s = s*__expf(m - mn) + __expf(val - mn);
        m = mn;
    }
    float inv = 1.f / s;
    #pragma unroll 8
    for (int i = 0; i < 128; ++i) {
        float val = base[i*stride];
        ob[i*stride] = f2bf(__expf(val - m) * inv);
    }
}

// ---------------- fused depthwise conv (combined taps) + residual ----------------
__global__ __launch_bounds__(256) void cnn_resid(
    const float* __restrict__ x, const float* __restrict__ wtc, float* __restrict__ out)
{
    const int tid = threadIdx.x;
    const int c0  = (tid & 127) * 4;
    const int s   = tid >> 7;
    const int g   = blockIdx.x * 2 + s;
    const int b   = blockIdx.z;
    const int i   = g >> 4;
    const int j0  = (g & 15) * 8;
    const float* xb = x + (size_t)b*HW*Cc;

    float4 acc[8];
    {
        float4 bias = *(const float4*)&wtc[49*Cc + c0];
        #pragma unroll
        for (int t = 0; t < 8; ++t) {
            float4 xv = *(const float4*)&xb[(size_t)(i*Ww + j0 + t)*Cc + c0];
            acc[t].x = bias.x + xv.x; acc[t].y = bias.y + xv.y;
            acc[t].z = bias.z + xv.z; acc[t].w = bias.w + xv.w;
        }
    }

    #pragma unroll
    for (int di = 0; di < 7; ++di) {
        int ii = i + di - 3;
        if (ii >= 0 && ii < Hh) {
            float4 xv[14];
            #pragma unroll
            for (int u = 0; u < 14; ++u) {
                int jj = j0 - 3 + u;
                if (jj >= 0 && jj < Ww) xv[u] = *(const float4*)&xb[(size_t)(ii*Ww + jj)*Cc + c0];
                else { xv[u].x = 0.f; xv[u].y = 0.f; xv[u].z = 0.f; xv[u].w = 0.f; }
            }
            #pragma unroll
            for (int dj = 0; dj < 7; ++dj) {
                float4 w = *(const float4*)&wtc[(di*7 + dj)*Cc + c0];
                #pragma unroll
                for (int t = 0; t < 8; ++t) {
                    acc[t].x = fmaf(xv[t+dj].x, w.x, acc[t].x);
                    acc[t].y = fmaf(xv[t+dj].y, w.y, acc[t].y);
                    acc[t].z = fmaf(xv[t+dj].z, w.z, acc[t].z);
                    acc[t].w = fmaf(xv[t+dj].w, w.w, acc[t].w);
                }
            }
        }
    }

    #pragma unroll
    for (int t = 0; t < 8; ++t)
        *(float4*)&out[((size_t)b*HW + i*Ww + j0 + t)*Cc + c0] = acc[t];
}

// ---------------- aggregation, bf16 MFMA: dest = base + gamma*(att @ V) ----------------
// A = attb[(b*2+mode)*128+L]  128r x 128k ; B = vt[b][L] 512c x 128k (c-sliced by blockIdx.y)
__global__ __launch_bounds__(256) void cc_agg_mfma(
    const unsigned short* __restrict__ attb, const unsigned short* __restrict__ vt,
    const float* __restrict__ base, float* __restrict__ dest,
    unsigned short* __restrict__ bfdup,
    const float* __restrict__ gamma_ptr, const int mode)
{
    const int L  = blockIdx.x;
    const int c0 = blockIdx.y * 128;
    const int b  = blockIdx.z;
    const unsigned short* A = attb + ((size_t)((b*2+mode)*128 + L))*16384;
    const unsigned short* B = vt + (((size_t)(b*128 + L))*Cc + c0)*128;

    __shared__ unsigned short Al[128][72];
    __shared__ unsigned short Bl[128][72];

    const int tid = threadIdx.x;
    const int wid = tid >> 6, lane = tid & 63;
    const int wm = wid >> 1, wn = wid & 1;
    const int lr = lane & 15, lg = lane >> 4;

    f32x4 acc[4][4];
    #pragma unroll
    for (int i = 0; i < 4; ++i)
        #pragma unroll
        for (int j = 0; j < 4; ++j) acc[i][j] = (f32x4){0.f,0.f,0.f,0.f};

    for (int k0 = 0; k0 < 128; k0 += 64) {
        __syncthreads();
        #pragma unroll
        for (int r = 0; r < 4; ++r) {
            int id = tid + r*256;
            int row = id >> 3, ch = id & 7;
            *(short8*)&Al[row][ch*8] = *(const short8*)&A[(size_t)row*128 + k0 + ch*8];
            *(short8*)&Bl[row][ch*8] = *(const short8*)&B[(size_t)row*128 + k0 + ch*8];
        }
        __syncthreads();
        #pragma unroll
        for (int ks = 0; ks < 2; ++ks) {
            short8 af[4], bf[4];
            #pragma unroll
            for (int mi = 0; mi < 4; ++mi) af[mi] = *(const short8*)&Al[wm*64 + mi*16 + lr][ks*32 + lg*8];
            #pragma unroll
            for (int ni = 0; ni < 4; ++ni) bf[ni] = *(const short8*)&Bl[wn*64 + ni*16 + lr][ks*32 + lg*8];
            #pragma unroll
            for (int mi = 0; mi < 4; ++mi)
                #pragma unroll
                for (int ni = 0; ni < 4; ++ni)
                    acc[mi][ni] = __builtin_amdgcn_mfma_f32_16x16x32_bf16(af[mi], bf[ni], acc[mi][ni], 0, 0, 0);
        }
    }

    const float g = gamma_ptr[0];
    #pragma unroll
    for (int mi = 0; mi < 4; ++mi)
        #pragma unroll
        for (int ni = 0; ni < 4; ++ni) {
            int c = c0 + wn*64 + ni*16 + lr;
            #pragma unroll
            for (int r = 0; r < 4; ++r) {
                int m = wm*64 + mi*16 + lg*4 + r;
                int ns = mode ? (L*128 + m) : (m*128 + L);
                size_t off = ((size_t)b*HW + ns)*Cc + c;
                float val = base[off] + g*acc[mi][ni][r];
                dest[off] = val;
                if (bfdup) bfdup[off] = f2bf(val);
            }
        }
}

extern "C" void kernel_launch(void* const* d_in, const int* in_sizes, int n_in,
                              void* d_out, int out_size, void* d_ws, size_t ws_size,
                              hipStream_t stream)
{
    const float* x     = (const float*)d_in[0];
    const float* wq    = (const float*)d_in[1];
    const float* bq    = (const float*)d_in[2];
    const float* wk    = (const float*)d_in[3];
    const float* bk    = (const float*)d_in[4];
    const float* wv    = (const float*)d_in[5];
    const float* bv    = (const float*)d_in[6];
    const float* gamma = (const float*)d_in[7];
    const float* wq1   = (const float*)d_in[8];
    const float* bq1   = (const float*)d_in[9];
    const float* wk1   = (const float*)d_in[10];
    const float* bk1   = (const float*)d_in[11];
    const float* wv1   = (const float*)d_in[12];
    const float* bv1   = (const float*)d_in[13];
    const float* gamma1= (const float*)d_in[14];
    const float* w7    = (const float*)d_in[15];
    const float* b7    = (const float*)d_in[16];
    const float* w5    = (const float*)d_in[17];
    const float* b5    = (const float*)d_in[18];
    const float* w3    = (const float*)d_in[19];
    const float* b3    = (const float*)d_in[20];
    float* outp = (float*)d_out;

    // fp32: qb(2.1M) kb(2.1M) eb(8.4M) wtc(25.6K) ; then ushort: xbf(16.8M) wb0 wb1 vbf/attb(16.8M,
    // aliased: vbf dead after vtrans, attb written after) vcol(16.8M) vrow(16.8M)  ~= 186 MB
    float* ws = (float*)d_ws;
    float* qb  = ws;
    float* kb  = qb + (size_t)2*HW*CQ;
    float* eb  = kb + (size_t)2*HW*CQ;
    float* wtc = eb + (size_t)2*2*128*16384;
    unsigned short* xbf  = (unsigned short*)(wtc + 50*Cc);
    unsigned short* wb0  = xbf + (size_t)2*HW*Cc;
    unsigned short* wb1  = wb0 + (size_t)640*Cc;
    unsigned short* vbf  = wb1 + (size_t)640*Cc;
    unsigned short* attb = vbf;                       // alias (see ordering)
    unsigned short* vcol = vbf + (size_t)2*HW*Cc;
    unsigned short* vrow = vcol + (size_t)2*HW*Cc;
    float* ob = outp;   // block-1 intermediate lives in d_out

    prep_weights<<<dim3(2), dim3(256), 0, stream>>>(w7,b7,w5,b5,w3,b3, wtc);
    prep_wbf    <<<dim3(320), dim3(256), 0, stream>>>(wq, wk, wv, wb0);
    prep_wbf    <<<dim3(320), dim3(256), 0, stream>>>(wq1, wk1, wv1, wb1);
    to_bf16     <<<dim3(2048), dim3(256), 0, stream>>>(x, xbf, 2*HW*Cc);

    // ---- criss-cross block 1 (input x) ----
    qkv_gemm_mfma<<<dim3(128,10,2), dim3(256), 0, stream>>>((const short*)xbf, (const short*)wb0,
                                                            bq,bk,bv, qb,kb, vbf);
    vtrans    <<<dim3(128,4,4),  dim3(256), 0, stream>>>(vbf, vcol, vrow);
    cc_scores <<<dim3(128,2,2),  dim3(256), 0, stream>>>(qb, kb, eb);
    cc_softmax<<<dim3(128,2,2),  dim3(128), 0, stream>>>(eb, attb);          // clobbers vbf (dead)
    cnn_resid <<<dim3(1024,1,2), dim3(256), 0, stream>>>(x, wtc, ob);        // ob = x + cnn_feat1
    cc_agg_mfma<<<dim3(128,4,2), dim3(256), 0, stream>>>(attb, vcol, ob, ob, nullptr, gamma, 0);
    cc_agg_mfma<<<dim3(128,4,2), dim3(256), 0, stream>>>(attb, vrow, ob, ob, xbf,    gamma, 1);

    // ---- criss-cross block 2 (input ob via xbf dup, residual ob, output d_out) ----
    qkv_gemm_mfma<<<dim3(128,10,2), dim3(256), 0, stream>>>((const short*)xbf, (const short*)wb1,
                                                            bq1,bk1,bv1, qb,kb, vbf);
    vtrans    <<<dim3(128,4,4),  dim3(256), 0, stream>>>(vbf, vcol, vrow);
    cc_scores <<<dim3(128,2,2),  dim3(256), 0, stream>>>(qb, kb, eb);
    cc_softmax<<<dim3(128,2,2),  dim3(128), 0, stream>>>(eb, attb);
    cc_agg_mfma<<<dim3(128,4,2), dim3(256), 0, stream>>>(attb, vcol, ob,   outp, nullptr, gamma1, 0);
    cc_agg_mfma<<<dim3(128,4,2), dim3(256), 0, stream>>>(attb, vrow, outp, outp, nullptr, gamma1, 1);
}

// Round 6
// 648.579 us; speedup vs baseline: 2.0893x; 1.0363x over previous
//
#include <hip/hip_runtime.h>
#include <hip/hip_bf16.h>

#define Hh 128
#define Ww 128
#define HW 16384
#define Cc 512
#define CQ 64

typedef __attribute__((ext_vector_type(8))) short short8;
typedef __attribute__((ext_vector_type(4))) float f32x4;

static __device__ __forceinline__ unsigned short f2bf(float f) {
    __hip_bfloat16 h = __float2bfloat16(f);
    return *(unsigned short*)&h;
}

// ---------------- prep: combined dwconv weights (7x7 taps with 5x5+3x3 folded in) ----------------
__global__ void prep_weights(const float* __restrict__ w7, const float* __restrict__ b7,
                             const float* __restrict__ w5, const float* __restrict__ b5,
                             const float* __restrict__ w3, const float* __restrict__ b3,
                             float* __restrict__ wtc)
{
    int c = blockIdx.x * 256 + threadIdx.x;
    if (c >= Cc) return;
    for (int di = 0; di < 7; ++di)
        for (int dj = 0; dj < 7; ++dj) {
            float w = w7[c*49 + di*7 + dj];
            if (di >= 1 && di <= 5 && dj >= 1 && dj <= 5) w += w5[c*25 + (di-1)*5 + (dj-1)];
            if (di >= 2 && di <= 4 && dj >= 2 && dj <= 4) w += w3[c*9  + (di-2)*3 + (dj-2)];
            wtc[(di*7+dj)*Cc + c] = w;
        }
    wtc[49*Cc + c] = b7[c] + b5[c] + b3[c];
}

// ---------------- convert fp32 -> bf16 (stream) ----------------
__global__ void to_bf16(const float* __restrict__ src, unsigned short* __restrict__ dst, int n)
{
    int stride = gridDim.x * 256 * 4;
    for (int i = (blockIdx.x*256 + threadIdx.x)*4; i < n; i += stride) {
        float4 v = *(const float4*)&src[i];
        ushort4 o;
        o.x = f2bf(v.x); o.y = f2bf(v.y); o.z = f2bf(v.z); o.w = f2bf(v.w);
        *(ushort4*)&dst[i] = o;
    }
}

// ---------------- QKV weights -> one bf16 matrix [640][512] ----------------
__global__ void prep_wbf(const float* __restrict__ wq, const float* __restrict__ wk,
                         const float* __restrict__ wv, unsigned short* __restrict__ wb)
{
    int e = (blockIdx.x*256 + threadIdx.x)*4;
    if (e >= 640*Cc) return;
    int row = e >> 9, col = e & 511;
    const float* s;
    if (row < 64)       s = wq + (size_t)row*Cc;
    else if (row < 128) s = wk + (size_t)(row-64)*Cc;
    else                s = wv + (size_t)(row-128)*Cc;
    float4 v = *(const float4*)&s[col];
    ushort4 o;
    o.x = f2bf(v.x); o.y = f2bf(v.y); o.z = f2bf(v.z); o.w = f2bf(v.w);
    *(ushort4*)&wb[e] = o;
}

// ---------------- fused QKV GEMM, bf16 MFMA (A=W, B=X swap => vectorized epilogue) ----------------
// BM=128, BN=128, BK=32. 4 waves 2(n)x2(m); wave tile N64 x M64; acc[ni][mi], D rows = n.
__global__ __launch_bounds__(256) void qkv_gemm_mfma(
    const short* __restrict__ xb, const short* __restrict__ wb,
    const float* __restrict__ bq, const float* __restrict__ bk, const float* __restrict__ bv,
    float* __restrict__ qo, float* __restrict__ ko, unsigned short* __restrict__ vbf)
{
    const int b  = blockIdx.z;
    const int m0 = blockIdx.x * 128;
    const int n0 = blockIdx.y * 128;           // 0..639 step 128; tile0 = Q|K, tiles 1-4 = V

    __shared__ short Wl[128][40];              // A operand: W rows (n) x k
    __shared__ short Xl[128][40];              // B operand: x rows (m) x k

    const int tid  = threadIdx.x;
    const int wid  = tid >> 6;
    const int lane = tid & 63;
    const int wn = wid >> 1, wm = wid & 1;
    const int lr = lane & 15, lg = lane >> 4;

    const short* Ag = wb + (size_t)n0*Cc;
    const short* Bg = xb + (size_t)b*HW*Cc + (size_t)m0*Cc;

    f32x4 acc[4][4];                           // [ni][mi]
    #pragma unroll
    for (int i = 0; i < 4; ++i)
        #pragma unroll
        for (int j = 0; j < 4; ++j) acc[i][j] = (f32x4){0.f,0.f,0.f,0.f};

    for (int k0 = 0; k0 < Cc; k0 += 32) {
        __syncthreads();
        #pragma unroll
        for (int r = 0; r < 2; ++r) {
            int idx = tid + r*256;
            int row = idx >> 2, ch = idx & 3;
            *(short8*)&Wl[row][ch*8] = *(const short8*)&Ag[(size_t)row*Cc + k0 + ch*8];
            *(short8*)&Xl[row][ch*8] = *(const short8*)&Bg[(size_t)row*Cc + k0 + ch*8];
        }
        __syncthreads();

        short8 af[4], bf[4];
        #pragma unroll
        for (int ni = 0; ni < 4; ++ni) af[ni] = *(const short8*)&Wl[wn*64 + ni*16 + lr][lg*8];
        #pragma unroll
        for (int mi = 0; mi < 4; ++mi) bf[mi] = *(const short8*)&Xl[wm*64 + mi*16 + lr][lg*8];
        #pragma unroll
        for (int ni = 0; ni < 4; ++ni)
            #pragma unroll
            for (int mi = 0; mi < 4; ++mi)
                acc[ni][mi] = __builtin_amdgcn_mfma_f32_16x16x32_bf16(af[ni], bf[mi], acc[ni][mi], 0, 0, 0);
    }

    if (n0 < 128) {                            // Q (n<64) | K (n>=64); wave-uniform by wn
        #pragma unroll
        for (int ni = 0; ni < 4; ++ni) {
            int n = wn*64 + ni*16 + lg*4;      // lane's 4 consecutive output channels
            const float* bias = (n < 64) ? bq : bk;
            float* Out = ((n < 64) ? qo : ko) + (size_t)b*HW*CQ;
            int col = n & 63;
            float4 b4 = *(const float4*)&bias[col];
            #pragma unroll
            for (int mi = 0; mi < 4; ++mi) {
                int m = m0 + wm*64 + mi*16 + lr;
                float4 o;
                o.x = acc[ni][mi][0] + b4.x; o.y = acc[ni][mi][1] + b4.y;
                o.z = acc[ni][mi][2] + b4.z; o.w = acc[ni][mi][3] + b4.w;
                *(float4*)&Out[(size_t)m*CQ + col] = o;
            }
        }
    } else {                                   // V -> bf16, ushort4
        unsigned short* Out = vbf + (size_t)b*HW*Cc;
        #pragma unroll
        for (int ni = 0; ni < 4; ++ni) {
            int col = (n0 - 128) + wn*64 + ni*16 + lg*4;
            float4 b4 = *(const float4*)&bv[col];
            #pragma unroll
            for (int mi = 0; mi < 4; ++mi) {
                int m = m0 + wm*64 + mi*16 + lr;
                ushort4 o;
                o.x = f2bf(acc[ni][mi][0] + b4.x); o.y = f2bf(acc[ni][mi][1] + b4.y);
                o.z = f2bf(acc[ni][mi][2] + b4.z); o.w = f2bf(acc[ni][mi][3] + b4.w);
                *(ushort4*)&Out[(size_t)m*Cc + col] = o;
            }
        }
    }
}

// ---------------- V transposes: vcol[b][j][c][k]=V[k*128+j][c], vrow[b][i][c][k]=V[i*128+k][c] ----
__global__ __launch_bounds__(256) void vtrans(
    const unsigned short* __restrict__ vbf,
    unsigned short* __restrict__ vcol, unsigned short* __restrict__ vrow)
{
    const int L  = blockIdx.x;
    const int ct = blockIdx.y;
    const int bz = blockIdx.z;
    const int b = bz >> 1, mode = bz & 1;
    const int tid = threadIdx.x;
    const int lk = tid & 15;
    const int lc = tid >> 4;
    const int c0 = ct*128 + lc*8;
    const unsigned short* src = vbf + (size_t)b*HW*Cc;

    short8 in[8];
    #pragma unroll
    for (int u = 0; u < 8; ++u) {
        int k = lk*8 + u;
        int row = mode ? L*128 + k : k*128 + L;
        in[u] = *(const short8*)&src[(size_t)row*Cc + c0];
    }
    unsigned short* dst = (mode ? vrow : vcol) + (((size_t)(b*128 + L))*Cc + c0)*128 + lk*8;
    #pragma unroll
    for (int t = 0; t < 8; ++t) {
        short8 o;
        #pragma unroll
        for (int u = 0; u < 8; ++u) o[u] = in[u][t];
        *(short8*)&dst[(size_t)t*128] = o;
    }
}

// ---------------- criss-cross scores (fp32) ----------------
__global__ __launch_bounds__(256) void cc_scores(
    const float* __restrict__ qi, const float* __restrict__ ki, float* __restrict__ e)
{
    const int L = blockIdx.x;
    const int mode = blockIdx.y;
    const int b = blockIdx.z;
    const float* qb = qi + (size_t)b*HW*CQ;
    const float* kb = ki + (size_t)b*HW*CQ;
    float* eb = e + ((size_t)((b*2+mode)*128 + L)) * 16384;

    __shared__ float Qs[16][132];
    __shared__ float Ks[16][132];
    const int tid = threadIdx.x;
    const int tx = tid & 15, ty = tid >> 4;

    float acc[8][8];
    #pragma unroll
    for (int i = 0; i < 8; ++i)
        #pragma unroll
        for (int j = 0; j < 8; ++j) acc[i][j] = 0.f;

    for (int c0 = 0; c0 < CQ; c0 += 16) {
        __syncthreads();
        #pragma unroll
        for (int r = 0; r < 2; ++r) {
            int t = tid + r*256;
            int row = t >> 2;
            int c4  = (t & 3) * 4;
            int n = (mode == 0) ? row*Ww + L : L*Ww + row;
            float4 a = *(const float4*)&qb[(size_t)n*CQ + c0 + c4];
            Qs[c4+0][row] = a.x; Qs[c4+1][row] = a.y; Qs[c4+2][row] = a.z; Qs[c4+3][row] = a.w;
            float4 kk4 = *(const float4*)&kb[(size_t)n*CQ + c0 + c4];
            Ks[c4+0][row] = kk4.x; Ks[c4+1][row] = kk4.y; Ks[c4+2][row] = kk4.z; Ks[c4+3][row] = kk4.w;
        }
        __syncthreads();
        #pragma unroll
        for (int cc = 0; cc < 16; ++cc) {
            float a0[8], b0[8];
            #pragma unroll
            for (int i = 0; i < 8; ++i) a0[i] = Qs[cc][ty*8+i];
            #pragma unroll
            for (int j = 0; j < 8; ++j) b0[j] = Ks[cc][tx*8+j];
            #pragma unroll
            for (int i = 0; i < 8; ++i)
                #pragma unroll
                for (int j = 0; j < 8; ++j) acc[i][j] = fmaf(a0[i], b0[j], acc[i][j]);
        }
    }

    #pragma unroll
    for (int i = 0; i < 8; ++i) {
        int r = ty*8 + i;
        float4 o0, o1;
        o0.x = acc[i][0]; o0.y = acc[i][1]; o0.z = acc[i][2]; o0.w = acc[i][3];
        o1.x = acc[i][4]; o1.y = acc[i][5]; o1.z = acc[i][6]; o1.w = acc[i][7];
        *(float4*)&eb[r*128 + tx*8 + 0] = o0;
        *(float4*)&eb[r*128 + tx*8 + 4] = o1;
    }
}

// ---------------- softmax over axis i; fp32 in -> bf16 att out ----------------
__global__ __launch_bounds__(128) void cc_softmax(const float* __restrict__ e,
                                                  unsigned short* __restrict__ attb)
{
    const int L = blockIdx.x, mode = blockIdx.y, b = blockIdx.z;
    const int k = threadIdx.x;
    size_t off; int stride;
    if (mode == 0) { off = ((size_t)(b*2)*128 + L)*16384 + k;        stride = 128;   }
    else           { off = ((size_t)(b*2+1)*128)*16384 + L*128 + k;  stride = 16384; }
    const float* base = e + off;
    unsigned short* ob = attb + off;
    float m = -1e30f, s = 0.f;
    #pragma unroll 8
    for (int i = 0; i < 128; ++i) {
        float val = base[i*stride];
        float mn = fmaxf(m, val);
        s = s*__expf(m - mn) + __expf(val - mn);
        m = mn;
    }
    float inv = 1.f / s;
    #pragma unroll 8
    for (int i = 0; i < 128; ++i) {
        float val = base[i*stride];
        ob[i*stride] = f2bf(__expf(val - m) * inv);
    }
}

// ---------------- fused depthwise conv + residual, XCD-chunked swizzle ----------------
__global__ __launch_bounds__(256) void cnn_resid(
    const float* __restrict__ x, const float* __restrict__ wtc, float* __restrict__ out)
{
    const int tid = threadIdx.x;
    const int c0  = (tid & 127) * 4;
    const int s   = tid >> 7;
    const int bx  = blockIdx.x;
    const int w   = ((bx & 7) << 7) | (bx >> 3);   // XCD-chunked: 128 consecutive work-ids per XCD
    const int g   = w * 2 + s;
    const int b   = blockIdx.z;
    const int i   = g >> 4;
    const int j0  = (g & 15) * 8;
    const float* xb = x + (size_t)b*HW*Cc;

    float4 acc[8];
    {
        float4 bias = *(const float4*)&wtc[49*Cc + c0];
        #pragma unroll
        for (int t = 0; t < 8; ++t) {
            float4 xv = *(const float4*)&xb[(size_t)(i*Ww + j0 + t)*Cc + c0];
            acc[t].x = bias.x + xv.x; acc[t].y = bias.y + xv.y;
            acc[t].z = bias.z + xv.z; acc[t].w = bias.w + xv.w;
        }
    }

    #pragma unroll
    for (int di = 0; di < 7; ++di) {
        int ii = i + di - 3;
        if (ii >= 0 && ii < Hh) {
            float4 xv[14];
            #pragma unroll
            for (int u = 0; u < 14; ++u) {
                int jj = j0 - 3 + u;
                if (jj >= 0 && jj < Ww) xv[u] = *(const float4*)&xb[(size_t)(ii*Ww + jj)*Cc + c0];
                else { xv[u].x = 0.f; xv[u].y = 0.f; xv[u].z = 0.f; xv[u].w = 0.f; }
            }
            #pragma unroll
            for (int dj = 0; dj < 7; ++dj) {
                float4 w4 = *(const float4*)&wtc[(di*7 + dj)*Cc + c0];
                #pragma unroll
                for (int t = 0; t < 8; ++t) {
                    acc[t].x = fmaf(xv[t+dj].x, w4.x, acc[t].x);
                    acc[t].y = fmaf(xv[t+dj].y, w4.y, acc[t].y);
                    acc[t].z = fmaf(xv[t+dj].z, w4.z, acc[t].z);
                    acc[t].w = fmaf(xv[t+dj].w, w4.w, acc[t].w);
                }
            }
        }
    }

    #pragma unroll
    for (int t = 0; t < 8; ++t)
        *(float4*)&out[((size_t)b*HW + i*Ww + j0 + t)*Cc + c0] = acc[t];
}

// ---------------- aggregation, bf16 MFMA (A=V, B=att swap => float4 epilogue) ----------------
// A = vt[b][L] c-rows x 128k (c-sliced); B = attb line m-rows x 128k. D[c][m]; lane holds 4 consec c.
__global__ __launch_bounds__(256) void cc_agg_mfma(
    const unsigned short* __restrict__ attb, const unsigned short* __restrict__ vt,
    const float* __restrict__ base, float* __restrict__ dest,
    unsigned short* __restrict__ bfdup,
    const float* __restrict__ gamma_ptr, const int mode)
{
    const int L  = blockIdx.x;
    const int c0 = blockIdx.y * 128;
    const int b  = blockIdx.z;
    const unsigned short* A = vt + (((size_t)(b*128 + L))*Cc + c0)*128;
    const unsigned short* Bm = attb + ((size_t)((b*2+mode)*128 + L))*16384;

    __shared__ unsigned short Vl[128][72];
    __shared__ unsigned short Ml[128][72];

    const int tid = threadIdx.x;
    const int wid = tid >> 6, lane = tid & 63;
    const int wc = wid >> 1, wm = wid & 1;
    const int lr = lane & 15, lg = lane >> 4;

    f32x4 acc[4][4];                            // [ci][mi]
    #pragma unroll
    for (int i = 0; i < 4; ++i)
        #pragma unroll
        for (int j = 0; j < 4; ++j) acc[i][j] = (f32x4){0.f,0.f,0.f,0.f};

    for (int k0 = 0; k0 < 128; k0 += 64) {
        __syncthreads();
        #pragma unroll
        for (int r = 0; r < 4; ++r) {
            int id = tid + r*256;
            int row = id >> 3, ch = id & 7;
            *(short8*)&Vl[row][ch*8] = *(const short8*)&A[(size_t)row*128 + k0 + ch*8];
            *(short8*)&Ml[row][ch*8] = *(const short8*)&Bm[(size_t)row*128 + k0 + ch*8];
        }
        __syncthreads();
        #pragma unroll
        for (int ks = 0; ks < 2; ++ks) {
            short8 af[4], bf[4];
            #pragma unroll
            for (int ci = 0; ci < 4; ++ci) af[ci] = *(const short8*)&Vl[wc*64 + ci*16 + lr][ks*32 + lg*8];
            #pragma unroll
            for (int mi = 0; mi < 4; ++mi) bf[mi] = *(const short8*)&Ml[wm*64 + mi*16 + lr][ks*32 + lg*8];
            #pragma unroll
            for (int ci = 0; ci < 4; ++ci)
                #pragma unroll
                for (int mi = 0; mi < 4; ++mi)
                    acc[ci][mi] = __builtin_amdgcn_mfma_f32_16x16x32_bf16(af[ci], bf[mi], acc[ci][mi], 0, 0, 0);
        }
    }

    const float g = gamma_ptr[0];
    #pragma unroll
    for (int ci = 0; ci < 4; ++ci) {
        int c = c0 + wc*64 + ci*16 + lg*4;      // 4 consecutive channels per lane
        #pragma unroll
        for (int mi = 0; mi < 4; ++mi) {
            int m = wm*64 + mi*16 + lr;
            int ns = mode ? (L*128 + m) : (m*128 + L);
            size_t off = ((size_t)b*HW + ns)*Cc + c;
            float4 bs = *(const float4*)&base[off];
            float4 o;
            o.x = bs.x + g*acc[ci][mi][0]; o.y = bs.y + g*acc[ci][mi][1];
            o.z = bs.z + g*acc[ci][mi][2]; o.w = bs.w + g*acc[ci][mi][3];
            *(float4*)&dest[off] = o;
            if (bfdup) {
                ushort4 d;
                d.x = f2bf(o.x); d.y = f2bf(o.y); d.z = f2bf(o.z); d.w = f2bf(o.w);
                *(ushort4*)&bfdup[off] = d;
            }
        }
    }
}

extern "C" void kernel_launch(void* const* d_in, const int* in_sizes, int n_in,
                              void* d_out, int out_size, void* d_ws, size_t ws_size,
                              hipStream_t stream)
{
    const float* x     = (const float*)d_in[0];
    const float* wq    = (const float*)d_in[1];
    const float* bq    = (const float*)d_in[2];
    const float* wk    = (const float*)d_in[3];
    const float* bk    = (const float*)d_in[4];
    const float* wv    = (const float*)d_in[5];
    const float* bv    = (const float*)d_in[6];
    const float* gamma = (const float*)d_in[7];
    const float* wq1   = (const float*)d_in[8];
    const float* bq1   = (const float*)d_in[9];
    const float* wk1   = (const float*)d_in[10];
    const float* bk1   = (const float*)d_in[11];
    const float* wv1   = (const float*)d_in[12];
    const float* bv1   = (const float*)d_in[13];
    const float* gamma1= (const float*)d_in[14];
    const float* w7    = (const float*)d_in[15];
    const float* b7    = (const float*)d_in[16];
    const float* w5    = (const float*)d_in[17];
    const float* b5    = (const float*)d_in[18];
    const float* w3    = (const float*)d_in[19];
    const float* b3    = (const float*)d_in[20];
    float* outp = (float*)d_out;

    float* ws = (float*)d_ws;
    float* qb  = ws;
    float* kb  = qb + (size_t)2*HW*CQ;
    float* eb  = kb + (size_t)2*HW*CQ;
    float* wtc = eb + (size_t)2*2*128*16384;
    unsigned short* xbf  = (unsigned short*)(wtc + 50*Cc);
    unsigned short* wb0  = xbf + (size_t)2*HW*Cc;
    unsigned short* wb1  = wb0 + (size_t)640*Cc;
    unsigned short* vbf  = wb1 + (size_t)640*Cc;
    unsigned short* attb = vbf;                       // alias (vbf dead after vtrans)
    unsigned short* vcol = vbf + (size_t)2*HW*Cc;
    unsigned short* vrow = vcol + (size_t)2*HW*Cc;
    float* ob = outp;   // block-1 intermediate lives in d_out

    prep_weights<<<dim3(2), dim3(256), 0, stream>>>(w7,b7,w5,b5,w3,b3, wtc);
    prep_wbf    <<<dim3(320), dim3(256), 0, stream>>>(wq, wk, wv, wb0);
    prep_wbf    <<<dim3(320), dim3(256), 0, stream>>>(wq1, wk1, wv1, wb1);
    to_bf16     <<<dim3(2048), dim3(256), 0, stream>>>(x, xbf, 2*HW*Cc);

    // ---- criss-cross block 1 (input x) ----
    qkv_gemm_mfma<<<dim3(128,5,2), dim3(256), 0, stream>>>((const short*)xbf, (const short*)wb0,
                                                           bq,bk,bv, qb,kb, vbf);
    vtrans    <<<dim3(128,4,4),  dim3(256), 0, stream>>>(vbf, vcol, vrow);
    cc_scores <<<dim3(128,2,2),  dim3(256), 0, stream>>>(qb, kb, eb);
    cc_softmax<<<dim3(128,2,2),  dim3(128), 0, stream>>>(eb, attb);          // clobbers vbf (dead)
    cnn_resid <<<dim3(1024,1,2), dim3(256), 0, stream>>>(x, wtc, ob);        // ob = x + cnn_feat1
    cc_agg_mfma<<<dim3(128,4,2), dim3(256), 0, stream>>>(attb, vcol, ob, ob, nullptr, gamma, 0);
    cc_agg_mfma<<<dim3(128,4,2), dim3(256), 0, stream>>>(attb, vrow, ob, ob, xbf,    gamma, 1);

    // ---- criss-cross block 2 (input ob via xbf dup, residual ob, output d_out) ----
    qkv_gemm_mfma<<<dim3(128,5,2), dim3(256), 0, stream>>>((const short*)xbf, (const short*)wb1,
                                                           bq1,bk1,bv1, qb,kb, vbf);
    vtrans    <<<dim3(128,4,4),  dim3(256), 0, stream>>>(vbf, vcol, vrow);
    cc_scores <<<dim3(128,2,2),  dim3(256), 0, stream>>>(qb, kb, eb);
    cc_softmax<<<dim3(128,2,2),  dim3(128), 0, stream>>>(eb, attb);
    cc_agg_mfma<<<dim3(128,4,2), dim3(256), 0, stream>>>(attb, vcol, ob,   outp, nullptr, gamma1, 0);
    cc_agg_mfma<<<dim3(128,4,2), dim3(256), 0, stream>>>(attb, vrow, outp, outp, nullptr, gamma1, 1);
}

// Round 7
// 563.294 us; speedup vs baseline: 2.4056x; 1.1514x over previous
//
#include <hip/hip_runtime.h>
#include <hip/hip_bf16.h>

#define Hh 128
#define Ww 128
#define HW 16384
#define Cc 512
#define CQ 64

typedef __attribute__((ext_vector_type(8))) short short8;
typedef __attribute__((ext_vector_type(4))) float f32x4;

static __device__ __forceinline__ unsigned short f2bf(float f) {
    __hip_bfloat16 h = __float2bfloat16(f);
    return *(unsigned short*)&h;
}
static __device__ __forceinline__ float bf2f(unsigned short u) {
    unsigned int v = ((unsigned int)u) << 16;
    return __uint_as_float(v);
}

// ---------------- prep: combined dwconv weights (7x7 taps with 5x5+3x3 folded in) ----------------
__global__ void prep_weights(const float* __restrict__ w7, const float* __restrict__ b7,
                             const float* __restrict__ w5, const float* __restrict__ b5,
                             const float* __restrict__ w3, const float* __restrict__ b3,
                             float* __restrict__ wtc)
{
    int c = blockIdx.x * 256 + threadIdx.x;
    if (c >= Cc) return;
    for (int di = 0; di < 7; ++di)
        for (int dj = 0; dj < 7; ++dj) {
            float w = w7[c*49 + di*7 + dj];
            if (di >= 1 && di <= 5 && dj >= 1 && dj <= 5) w += w5[c*25 + (di-1)*5 + (dj-1)];
            if (di >= 2 && di <= 4 && dj >= 2 && dj <= 4) w += w3[c*9  + (di-2)*3 + (dj-2)];
            wtc[(di*7+dj)*Cc + c] = w;
        }
    wtc[49*Cc + c] = b7[c] + b5[c] + b3[c];
}

// ---------------- convert fp32 -> bf16 (stream) ----------------
__global__ void to_bf16(const float* __restrict__ src, unsigned short* __restrict__ dst, int n)
{
    int stride = gridDim.x * 256 * 4;
    for (int i = (blockIdx.x*256 + threadIdx.x)*4; i < n; i += stride) {
        float4 v = *(const float4*)&src[i];
        ushort4 o;
        o.x = f2bf(v.x); o.y = f2bf(v.y); o.z = f2bf(v.z); o.w = f2bf(v.w);
        *(ushort4*)&dst[i] = o;
    }
}

// ---------------- QKV weights -> one bf16 matrix [640][512] ----------------
__global__ void prep_wbf(const float* __restrict__ wq, const float* __restrict__ wk,
                         const float* __restrict__ wv, unsigned short* __restrict__ wb)
{
    int e = (blockIdx.x*256 + threadIdx.x)*4;
    if (e >= 640*Cc) return;
    int row = e >> 9, col = e & 511;
    const float* s;
    if (row < 64)       s = wq + (size_t)row*Cc;
    else if (row < 128) s = wk + (size_t)(row-64)*Cc;
    else                s = wv + (size_t)(row-128)*Cc;
    float4 v = *(const float4*)&s[col];
    ushort4 o;
    o.x = f2bf(v.x); o.y = f2bf(v.y); o.z = f2bf(v.z); o.w = f2bf(v.w);
    *(ushort4*)&wb[e] = o;
}

// ---------------- fused QKV GEMM, bf16 MFMA (A=W, B=X => vectorized epilogue) ----------------
__global__ __launch_bounds__(256) void qkv_gemm_mfma(
    const short* __restrict__ xb, const short* __restrict__ wb,
    const float* __restrict__ bq, const float* __restrict__ bk, const float* __restrict__ bv,
    float* __restrict__ qo, float* __restrict__ ko, unsigned short* __restrict__ vbf)
{
    const int b  = blockIdx.z;
    const int m0 = blockIdx.x * 128;
    const int n0 = blockIdx.y * 128;           // 0..639 step 128; tile0 = Q|K, tiles 1-4 = V

    __shared__ short Wl[128][40];              // A operand: W rows (n) x k
    __shared__ short Xl[128][40];              // B operand: x rows (m) x k

    const int tid  = threadIdx.x;
    const int wid  = tid >> 6;
    const int lane = tid & 63;
    const int wn = wid >> 1, wm = wid & 1;
    const int lr = lane & 15, lg = lane >> 4;

    const short* Ag = wb + (size_t)n0*Cc;
    const short* Bg = xb + (size_t)b*HW*Cc + (size_t)m0*Cc;

    f32x4 acc[4][4];                           // [ni][mi]
    #pragma unroll
    for (int i = 0; i < 4; ++i)
        #pragma unroll
        for (int j = 0; j < 4; ++j) acc[i][j] = (f32x4){0.f,0.f,0.f,0.f};

    for (int k0 = 0; k0 < Cc; k0 += 32) {
        __syncthreads();
        #pragma unroll
        for (int r = 0; r < 2; ++r) {
            int idx = tid + r*256;
            int row = idx >> 2, ch = idx & 3;
            *(short8*)&Wl[row][ch*8] = *(const short8*)&Ag[(size_t)row*Cc + k0 + ch*8];
            *(short8*)&Xl[row][ch*8] = *(const short8*)&Bg[(size_t)row*Cc + k0 + ch*8];
        }
        __syncthreads();

        short8 af[4], bf[4];
        #pragma unroll
        for (int ni = 0; ni < 4; ++ni) af[ni] = *(const short8*)&Wl[wn*64 + ni*16 + lr][lg*8];
        #pragma unroll
        for (int mi = 0; mi < 4; ++mi) bf[mi] = *(const short8*)&Xl[wm*64 + mi*16 + lr][lg*8];
        #pragma unroll
        for (int ni = 0; ni < 4; ++ni)
            #pragma unroll
            for (int mi = 0; mi < 4; ++mi)
                acc[ni][mi] = __builtin_amdgcn_mfma_f32_16x16x32_bf16(af[ni], bf[mi], acc[ni][mi], 0, 0, 0);
    }

    if (n0 < 128) {                            // Q (n<64) | K (n>=64); wave-uniform by wn
        #pragma unroll
        for (int ni = 0; ni < 4; ++ni) {
            int n = wn*64 + ni*16 + lg*4;
            const float* bias = (n < 64) ? bq : bk;
            float* Out = ((n < 64) ? qo : ko) + (size_t)b*HW*CQ;
            int col = n & 63;
            float4 b4 = *(const float4*)&bias[col];
            #pragma unroll
            for (int mi = 0; mi < 4; ++mi) {
                int m = m0 + wm*64 + mi*16 + lr;
                float4 o;
                o.x = acc[ni][mi][0] + b4.x; o.y = acc[ni][mi][1] + b4.y;
                o.z = acc[ni][mi][2] + b4.z; o.w = acc[ni][mi][3] + b4.w;
                *(float4*)&Out[(size_t)m*CQ + col] = o;
            }
        }
    } else {                                   // V -> bf16, ushort4
        unsigned short* Out = vbf + (size_t)b*HW*Cc;
        #pragma unroll
        for (int ni = 0; ni < 4; ++ni) {
            int col = (n0 - 128) + wn*64 + ni*16 + lg*4;
            float4 b4 = *(const float4*)&bv[col];
            #pragma unroll
            for (int mi = 0; mi < 4; ++mi) {
                int m = m0 + wm*64 + mi*16 + lr;
                ushort4 o;
                o.x = f2bf(acc[ni][mi][0] + b4.x); o.y = f2bf(acc[ni][mi][1] + b4.y);
                o.z = f2bf(acc[ni][mi][2] + b4.z); o.w = f2bf(acc[ni][mi][3] + b4.w);
                *(ushort4*)&Out[(size_t)m*Cc + col] = o;
            }
        }
    }
}

// ---------------- V transposes: vcol[b][j][c][k]=V[k*128+j][c], vrow[b][i][c][k]=V[i*128+k][c] ----
__global__ __launch_bounds__(256) void vtrans(
    const unsigned short* __restrict__ vbf,
    unsigned short* __restrict__ vcol, unsigned short* __restrict__ vrow)
{
    const int L  = blockIdx.x;
    const int ct = blockIdx.y;
    const int bz = blockIdx.z;
    const int b = bz >> 1, mode = bz & 1;
    const int tid = threadIdx.x;
    const int lk = tid & 15;
    const int lc = tid >> 4;
    const int c0 = ct*128 + lc*8;
    const unsigned short* src = vbf + (size_t)b*HW*Cc;

    short8 in[8];
    #pragma unroll
    for (int u = 0; u < 8; ++u) {
        int k = lk*8 + u;
        int row = mode ? L*128 + k : k*128 + L;
        in[u] = *(const short8*)&src[(size_t)row*Cc + c0];
    }
    unsigned short* dst = (mode ? vrow : vcol) + (((size_t)(b*128 + L))*Cc + c0)*128 + lk*8;
    #pragma unroll
    for (int t = 0; t < 8; ++t) {
        short8 o;
        #pragma unroll
        for (int u = 0; u < 8; ++u) o[u] = in[u][t];
        *(short8*)&dst[(size_t)t*128] = o;
    }
}

// ---------------- criss-cross scores (fp32) ----------------
__global__ __launch_bounds__(256) void cc_scores(
    const float* __restrict__ qi, const float* __restrict__ ki, float* __restrict__ e)
{
    const int L = blockIdx.x;
    const int mode = blockIdx.y;
    const int b = blockIdx.z;
    const float* qb = qi + (size_t)b*HW*CQ;
    const float* kb = ki + (size_t)b*HW*CQ;
    float* eb = e + ((size_t)((b*2+mode)*128 + L)) * 16384;

    __shared__ float Qs[16][132];
    __shared__ float Ks[16][132];
    const int tid = threadIdx.x;
    const int tx = tid & 15, ty = tid >> 4;

    float acc[8][8];
    #pragma unroll
    for (int i = 0; i < 8; ++i)
        #pragma unroll
        for (int j = 0; j < 8; ++j) acc[i][j] = 0.f;

    for (int c0 = 0; c0 < CQ; c0 += 16) {
        __syncthreads();
        #pragma unroll
        for (int r = 0; r < 2; ++r) {
            int t = tid + r*256;
            int row = t >> 2;
            int c4  = (t & 3) * 4;
            int n = (mode == 0) ? row*Ww + L : L*Ww + row;
            float4 a = *(const float4*)&qb[(size_t)n*CQ + c0 + c4];
            Qs[c4+0][row] = a.x; Qs[c4+1][row] = a.y; Qs[c4+2][row] = a.z; Qs[c4+3][row] = a.w;
            float4 kk4 = *(const float4*)&kb[(size_t)n*CQ + c0 + c4];
            Ks[c4+0][row] = kk4.x; Ks[c4+1][row] = kk4.y; Ks[c4+2][row] = kk4.z; Ks[c4+3][row] = kk4.w;
        }
        __syncthreads();
        #pragma unroll
        for (int cc = 0; cc < 16; ++cc) {
            float a0[8], b0[8];
            #pragma unroll
            for (int i = 0; i < 8; ++i) a0[i] = Qs[cc][ty*8+i];
            #pragma unroll
            for (int j = 0; j < 8; ++j) b0[j] = Ks[cc][tx*8+j];
            #pragma unroll
            for (int i = 0; i < 8; ++i)
                #pragma unroll
                for (int j = 0; j < 8; ++j) acc[i][j] = fmaf(a0[i], b0[j], acc[i][j]);
        }
    }

    #pragma unroll
    for (int i = 0; i < 8; ++i) {
        int r = ty*8 + i;
        float4 o0, o1;
        o0.x = acc[i][0]; o0.y = acc[i][1]; o0.z = acc[i][2]; o0.w = acc[i][3];
        o1.x = acc[i][4]; o1.y = acc[i][5]; o1.z = acc[i][6]; o1.w = acc[i][7];
        *(float4*)&eb[r*128 + tx*8 + 0] = o0;
        *(float4*)&eb[r*128 + tx*8 + 4] = o1;
    }
}

// ---------------- softmax over axis i; fp32 in -> bf16 att out ----------------
__global__ __launch_bounds__(128) void cc_softmax(const float* __restrict__ e,
                                                  unsigned short* __restrict__ attb)
{
    const int L = blockIdx.x, mode = blockIdx.y, b = blockIdx.z;
    const int k = threadIdx.x;
    size_t off; int stride;
    if (mode == 0) { off = ((size_t)(b*2)*128 + L)*16384 + k;        stride = 128;   }
    else           { off = ((size_t)(b*2+1)*128)*16384 + L*128 + k;  stride = 16384; }
    const float* base = e + off;
    unsigned short* ob = attb + off;
    float m = -1e30f, s = 0.f;
    #pragma unroll 8
    for (int i = 0; i < 128; ++i) {
        float val = base[i*stride];
        float mn = fmaxf(m, val);
        s = s*__expf(m - mn) + __expf(val - mn);
        m = mn;
    }
    float inv = 1.f / s;
    #pragma unroll 8
    for (int i = 0; i < 128; ++i) {
        float val = base[i*stride];
        ob[i*stride] = f2bf(__expf(val - m) * inv);
    }
}

// ---------------- fused depthwise conv + residual, bf16 input, XCD-chunked swizzle ----------------
__global__ __launch_bounds__(256) void cnn_resid(
    const unsigned short* __restrict__ xb16, const float* __restrict__ wtc, float* __restrict__ out)
{
    const int tid = threadIdx.x;
    const int c0  = (tid & 127) * 4;
    const int s   = tid >> 7;
    const int bx  = blockIdx.x;
    const int w   = ((bx & 7) << 7) | (bx >> 3);   // XCD-chunked: 128 consecutive work-ids per XCD
    const int g   = w * 2 + s;
    const int b   = blockIdx.z;
    const int i   = g >> 4;
    const int j0  = (g & 15) * 8;
    const unsigned short* xb = xb16 + (size_t)b*HW*Cc;

    float4 acc[8];
    {
        float4 bias = *(const float4*)&wtc[49*Cc + c0];
        #pragma unroll
        for (int t = 0; t < 8; ++t) {
            ushort4 u = *(const ushort4*)&xb[(size_t)(i*Ww + j0 + t)*Cc + c0];
            acc[t].x = bias.x + bf2f(u.x); acc[t].y = bias.y + bf2f(u.y);
            acc[t].z = bias.z + bf2f(u.z); acc[t].w = bias.w + bf2f(u.w);
        }
    }

    #pragma unroll
    for (int di = 0; di < 7; ++di) {
        int ii = i + di - 3;
        if (ii >= 0 && ii < Hh) {
            float4 xv[14];
            #pragma unroll
            for (int u = 0; u < 14; ++u) {
                int jj = j0 - 3 + u;
                if (jj >= 0 && jj < Ww) {
                    ushort4 uu = *(const ushort4*)&xb[(size_t)(ii*Ww + jj)*Cc + c0];
                    xv[u].x = bf2f(uu.x); xv[u].y = bf2f(uu.y);
                    xv[u].z = bf2f(uu.z); xv[u].w = bf2f(uu.w);
                } else { xv[u].x = 0.f; xv[u].y = 0.f; xv[u].z = 0.f; xv[u].w = 0.f; }
            }
            #pragma unroll
            for (int dj = 0; dj < 7; ++dj) {
                float4 w4 = *(const float4*)&wtc[(di*7 + dj)*Cc + c0];
                #pragma unroll
                for (int t = 0; t < 8; ++t) {
                    acc[t].x = fmaf(xv[t+dj].x, w4.x, acc[t].x);
                    acc[t].y = fmaf(xv[t+dj].y, w4.y, acc[t].y);
                    acc[t].z = fmaf(xv[t+dj].z, w4.z, acc[t].z);
                    acc[t].w = fmaf(xv[t+dj].w, w4.w, acc[t].w);
                }
            }
        }
    }

    #pragma unroll
    for (int t = 0; t < 8; ++t)
        *(float4*)&out[((size_t)b*HW + i*Ww + j0 + t)*Cc + c0] = acc[t];
}

// ---------------- aggregation, bf16 MFMA + LDS-staged coalesced epilogue ----------------
// A = vt[b][L] c-rows x 128k (c-sliced); B = attb line m-rows x 128k. D[c][m].
// Epilogue: stage 64 m-rows x 128 c in LDS (XOR-swizzled), write 512B segments.
__global__ __launch_bounds__(256) void cc_agg_mfma(
    const unsigned short* __restrict__ attb, const unsigned short* __restrict__ vt,
    const float* __restrict__ base, float* __restrict__ dest,
    unsigned short* __restrict__ bfdup,
    const float* __restrict__ gamma_ptr, const int mode)
{
    const int L  = blockIdx.x;
    const int c0 = blockIdx.y * 128;
    const int b  = blockIdx.z;
    const unsigned short* A = vt + (((size_t)(b*128 + L))*Cc + c0)*128;
    const unsigned short* Bm = attb + ((size_t)((b*2+mode)*128 + L))*16384;

    __shared__ __align__(16) char smem[36864];
    auto Vl = (unsigned short (*)[72])smem;            // 128x72 ushort = 18432B
    auto Ml = (unsigned short (*)[72])(smem + 18432);  // 128x72 ushort = 18432B
    auto St = (float (*)[128])smem;                    // 64x128 f32    = 32768B (aliases)

    const int tid = threadIdx.x;
    const int wid = tid >> 6, lane = tid & 63;
    const int wc = wid >> 1, wm = wid & 1;
    const int lr = lane & 15, lg = lane >> 4;

    f32x4 acc[4][4];                            // [ci][mi]
    #pragma unroll
    for (int i = 0; i < 4; ++i)
        #pragma unroll
        for (int j = 0; j < 4; ++j) acc[i][j] = (f32x4){0.f,0.f,0.f,0.f};

    for (int k0 = 0; k0 < 128; k0 += 64) {
        __syncthreads();
        #pragma unroll
        for (int r = 0; r < 4; ++r) {
            int id = tid + r*256;
            int row = id >> 3, ch = id & 7;
            *(short8*)&Vl[row][ch*8] = *(const short8*)&A[(size_t)row*128 + k0 + ch*8];
            *(short8*)&Ml[row][ch*8] = *(const short8*)&Bm[(size_t)row*128 + k0 + ch*8];
        }
        __syncthreads();
        #pragma unroll
        for (int ks = 0; ks < 2; ++ks) {
            short8 af[4], bf[4];
            #pragma unroll
            for (int ci = 0; ci < 4; ++ci) af[ci] = *(const short8*)&Vl[wc*64 + ci*16 + lr][ks*32 + lg*8];
            #pragma unroll
            for (int mi = 0; mi < 4; ++mi) bf[mi] = *(const short8*)&Ml[wm*64 + mi*16 + lr][ks*32 + lg*8];
            #pragma unroll
            for (int ci = 0; ci < 4; ++ci)
                #pragma unroll
                for (int mi = 0; mi < 4; ++mi)
                    acc[ci][mi] = __builtin_amdgcn_mfma_f32_16x16x32_bf16(af[ci], bf[mi], acc[ci][mi], 0, 0, 0);
        }
    }

    const float g = gamma_ptr[0];
    #pragma unroll
    for (int s = 0; s < 2; ++s) {               // m-half
        __syncthreads();                         // LDS reuse safe (k-loop / prev stage done)
        if (wm == s) {
            #pragma unroll
            for (int ci = 0; ci < 4; ++ci)
                #pragma unroll
                for (int mi = 0; mi < 4; ++mi) {
                    int ml = mi*16 + lr;
                    int cl = (wc*64 + ci*16 + lg*4) ^ ((ml & 7) << 2);
                    *(f32x4*)&St[ml][cl] = acc[ci][mi];
                }
        }
        __syncthreads();
        #pragma unroll
        for (int it = 0; it < 8; ++it) {
            int ml = it*8 + (tid >> 5);          // 0..63
            int cl = (tid & 31) * 4;
            int m  = s*64 + ml;
            int ns = mode ? (L*128 + m) : (m*128 + L);
            size_t off = ((size_t)b*HW + ns)*Cc + c0 + cl;
            f32x4 v = *(f32x4*)&St[ml][cl ^ ((ml & 7) << 2)];
            float4 bs = *(const float4*)&base[off];
            float4 o;
            o.x = bs.x + g*v[0]; o.y = bs.y + g*v[1];
            o.z = bs.z + g*v[2]; o.w = bs.w + g*v[3];
            *(float4*)&dest[off] = o;
            if (bfdup) {
                ushort4 d;
                d.x = f2bf(o.x); d.y = f2bf(o.y); d.z = f2bf(o.z); d.w = f2bf(o.w);
                *(ushort4*)&bfdup[off] = d;
            }
        }
    }
}

extern "C" void kernel_launch(void* const* d_in, const int* in_sizes, int n_in,
                              void* d_out, int out_size, void* d_ws, size_t ws_size,
                              hipStream_t stream)
{
    const float* x     = (const float*)d_in[0];
    const float* wq    = (const float*)d_in[1];
    const float* bq    = (const float*)d_in[2];
    const float* wk    = (const float*)d_in[3];
    const float* bk    = (const float*)d_in[4];
    const float* wv    = (const float*)d_in[5];
    const float* bv    = (const float*)d_in[6];
    const float* gamma = (const float*)d_in[7];
    const float* wq1   = (const float*)d_in[8];
    const float* bq1   = (const float*)d_in[9];
    const float* wk1   = (const float*)d_in[10];
    const float* bk1   = (const float*)d_in[11];
    const float* wv1   = (const float*)d_in[12];
    const float* bv1   = (const float*)d_in[13];
    const float* gamma1= (const float*)d_in[14];
    const float* w7    = (const float*)d_in[15];
    const float* b7    = (const float*)d_in[16];
    const float* w5    = (const float*)d_in[17];
    const float* b5    = (const float*)d_in[18];
    const float* w3    = (const float*)d_in[19];
    const float* b3    = (const float*)d_in[20];
    float* outp = (float*)d_out;

    float* ws = (float*)d_ws;
    float* qb  = ws;
    float* kb  = qb + (size_t)2*HW*CQ;
    float* eb  = kb + (size_t)2*HW*CQ;
    float* wtc = eb + (size_t)2*2*128*16384;
    unsigned short* xbf  = (unsigned short*)(wtc + 50*Cc);
    unsigned short* wb0  = xbf + (size_t)2*HW*Cc;
    unsigned short* wb1  = wb0 + (size_t)640*Cc;
    unsigned short* vbf  = wb1 + (size_t)640*Cc;
    unsigned short* attb = vbf;                       // alias (vbf dead after vtrans)
    unsigned short* vcol = vbf + (size_t)2*HW*Cc;
    unsigned short* vrow = vcol + (size_t)2*HW*Cc;
    float* ob = outp;   // block-1 intermediate lives in d_out

    prep_weights<<<dim3(2), dim3(256), 0, stream>>>(w7,b7,w5,b5,w3,b3, wtc);
    prep_wbf    <<<dim3(320), dim3(256), 0, stream>>>(wq, wk, wv, wb0);
    prep_wbf    <<<dim3(320), dim3(256), 0, stream>>>(wq1, wk1, wv1, wb1);
    to_bf16     <<<dim3(2048), dim3(256), 0, stream>>>(x, xbf, 2*HW*Cc);

    // ---- criss-cross block 1 (input x) ----
    qkv_gemm_mfma<<<dim3(128,5,2), dim3(256), 0, stream>>>((const short*)xbf, (const short*)wb0,
                                                           bq,bk,bv, qb,kb, vbf);
    vtrans    <<<dim3(128,4,4),  dim3(256), 0, stream>>>(vbf, vcol, vrow);
    cc_scores <<<dim3(128,2,2),  dim3(256), 0, stream>>>(qb, kb, eb);
    cc_softmax<<<dim3(128,2,2),  dim3(128), 0, stream>>>(eb, attb);          // clobbers vbf (dead)
    cnn_resid <<<dim3(1024,1,2), dim3(256), 0, stream>>>(xbf, wtc, ob);      // ob = x + cnn_feat1
    cc_agg_mfma<<<dim3(128,4,2), dim3(256), 0, stream>>>(attb, vcol, ob, ob, nullptr, gamma, 0);
    cc_agg_mfma<<<dim3(128,4,2), dim3(256), 0, stream>>>(attb, vrow, ob, ob, xbf,    gamma, 1);

    // ---- criss-cross block 2 (input ob via xbf dup, residual ob, output d_out) ----
    qkv_gemm_mfma<<<dim3(128,5,2), dim3(256), 0, stream>>>((const short*)xbf, (const short*)wb1,
                                                           bq1,bk1,bv1, qb,kb, vbf);
    vtrans    <<<dim3(128,4,4),  dim3(256), 0, stream>>>(vbf, vcol, vrow);
    cc_scores <<<dim3(128,2,2),  dim3(256), 0, stream>>>(qb, kb, eb);
    cc_softmax<<<dim3(128,2,2),  dim3(128), 0, stream>>>(eb, attb);
    cc_agg_mfma<<<dim3(128,4,2), dim3(256), 0, stream>>>(attb, vcol, ob,   outp, nullptr, gamma1, 0);
    cc_agg_mfma<<<dim3(128,4,2), dim3(256), 0, stream>>>(attb, vrow, outp, outp, nullptr, gamma1, 1);
}

// Round 8
// 537.139 us; speedup vs baseline: 2.5227x; 1.0487x over previous
//
#include <hip/hip_runtime.h>
#include <hip/hip_bf16.h>

#define Hh 128
#define Ww 128
#define HW 16384
#define Cc 512
#define CQ 64

typedef __attribute__((ext_vector_type(8))) short short8;
typedef __attribute__((ext_vector_type(4))) float f32x4;

static __device__ __forceinline__ unsigned short f2bf(float f) {
    __hip_bfloat16 h = __float2bfloat16(f);
    return *(unsigned short*)&h;
}
static __device__ __forceinline__ float bf2f(unsigned short u) {
    unsigned int v = ((unsigned int)u) << 16;
    return __uint_as_float(v);
}

// ---------------- prep: combined dwconv weights (7x7 taps with 5x5+3x3 folded in) ----------------
__global__ void prep_weights(const float* __restrict__ w7, const float* __restrict__ b7,
                             const float* __restrict__ w5, const float* __restrict__ b5,
                             const float* __restrict__ w3, const float* __restrict__ b3,
                             float* __restrict__ wtc)
{
    int c = blockIdx.x * 256 + threadIdx.x;
    if (c >= Cc) return;
    for (int di = 0; di < 7; ++di)
        for (int dj = 0; dj < 7; ++dj) {
            float w = w7[c*49 + di*7 + dj];
            if (di >= 1 && di <= 5 && dj >= 1 && dj <= 5) w += w5[c*25 + (di-1)*5 + (dj-1)];
            if (di >= 2 && di <= 4 && dj >= 2 && dj <= 4) w += w3[c*9  + (di-2)*3 + (dj-2)];
            wtc[(di*7+dj)*Cc + c] = w;
        }
    wtc[49*Cc + c] = b7[c] + b5[c] + b3[c];
}

// ---------------- convert fp32 -> bf16 (stream) ----------------
__global__ void to_bf16(const float* __restrict__ src, unsigned short* __restrict__ dst, int n)
{
    int stride = gridDim.x * 256 * 4;
    for (int i = (blockIdx.x*256 + threadIdx.x)*4; i < n; i += stride) {
        float4 v = *(const float4*)&src[i];
        ushort4 o;
        o.x = f2bf(v.x); o.y = f2bf(v.y); o.z = f2bf(v.z); o.w = f2bf(v.w);
        *(ushort4*)&dst[i] = o;
    }
}

// ---------------- QKV weights -> one bf16 matrix [640][512] ----------------
__global__ void prep_wbf(const float* __restrict__ wq, const float* __restrict__ wk,
                         const float* __restrict__ wv, unsigned short* __restrict__ wb)
{
    int e = (blockIdx.x*256 + threadIdx.x)*4;
    if (e >= 640*Cc) return;
    int row = e >> 9, col = e & 511;
    const float* s;
    if (row < 64)       s = wq + (size_t)row*Cc;
    else if (row < 128) s = wk + (size_t)(row-64)*Cc;
    else                s = wv + (size_t)(row-128)*Cc;
    float4 v = *(const float4*)&s[col];
    ushort4 o;
    o.x = f2bf(v.x); o.y = f2bf(v.y); o.z = f2bf(v.z); o.w = f2bf(v.w);
    *(ushort4*)&wb[e] = o;
}

// ---------------- fused QKV GEMM, bf16 MFMA; Q,K,V all bf16 out ----------------
__global__ __launch_bounds__(256) void qkv_gemm_mfma(
    const short* __restrict__ xb, const short* __restrict__ wb,
    const float* __restrict__ bq, const float* __restrict__ bk, const float* __restrict__ bv,
    unsigned short* __restrict__ qo, unsigned short* __restrict__ ko,
    unsigned short* __restrict__ vbf)
{
    const int b  = blockIdx.z;
    const int m0 = blockIdx.x * 128;
    const int n0 = blockIdx.y * 128;           // 0..639 step 128; tile0 = Q|K, tiles 1-4 = V

    __shared__ short Wl[128][40];              // A operand: W rows (n) x k
    __shared__ short Xl[128][40];              // B operand: x rows (m) x k

    const int tid  = threadIdx.x;
    const int wid  = tid >> 6;
    const int lane = tid & 63;
    const int wn = wid >> 1, wm = wid & 1;
    const int lr = lane & 15, lg = lane >> 4;

    const short* Ag = wb + (size_t)n0*Cc;
    const short* Bg = xb + (size_t)b*HW*Cc + (size_t)m0*Cc;

    f32x4 acc[4][4];                           // [ni][mi]
    #pragma unroll
    for (int i = 0; i < 4; ++i)
        #pragma unroll
        for (int j = 0; j < 4; ++j) acc[i][j] = (f32x4){0.f,0.f,0.f,0.f};

    for (int k0 = 0; k0 < Cc; k0 += 32) {
        __syncthreads();
        #pragma unroll
        for (int r = 0; r < 2; ++r) {
            int idx = tid + r*256;
            int row = idx >> 2, ch = idx & 3;
            *(short8*)&Wl[row][ch*8] = *(const short8*)&Ag[(size_t)row*Cc + k0 + ch*8];
            *(short8*)&Xl[row][ch*8] = *(const short8*)&Bg[(size_t)row*Cc + k0 + ch*8];
        }
        __syncthreads();

        short8 af[4], bf[4];
        #pragma unroll
        for (int ni = 0; ni < 4; ++ni) af[ni] = *(const short8*)&Wl[wn*64 + ni*16 + lr][lg*8];
        #pragma unroll
        for (int mi = 0; mi < 4; ++mi) bf[mi] = *(const short8*)&Xl[wm*64 + mi*16 + lr][lg*8];
        #pragma unroll
        for (int ni = 0; ni < 4; ++ni)
            #pragma unroll
            for (int mi = 0; mi < 4; ++mi)
                acc[ni][mi] = __builtin_amdgcn_mfma_f32_16x16x32_bf16(af[ni], bf[mi], acc[ni][mi], 0, 0, 0);
    }

    if (n0 < 128) {                            // Q (n<64) | K (n>=64) -> bf16
        #pragma unroll
        for (int ni = 0; ni < 4; ++ni) {
            int n = wn*64 + ni*16 + lg*4;
            const float* bias = (n < 64) ? bq : bk;
            unsigned short* Out = ((n < 64) ? qo : ko) + (size_t)b*HW*CQ;
            int col = n & 63;
            float4 b4 = *(const float4*)&bias[col];
            #pragma unroll
            for (int mi = 0; mi < 4; ++mi) {
                int m = m0 + wm*64 + mi*16 + lr;
                ushort4 o;
                o.x = f2bf(acc[ni][mi][0] + b4.x); o.y = f2bf(acc[ni][mi][1] + b4.y);
                o.z = f2bf(acc[ni][mi][2] + b4.z); o.w = f2bf(acc[ni][mi][3] + b4.w);
                *(ushort4*)&Out[(size_t)m*CQ + col] = o;
            }
        }
    } else {                                   // V -> bf16
        unsigned short* Out = vbf + (size_t)b*HW*Cc;
        #pragma unroll
        for (int ni = 0; ni < 4; ++ni) {
            int col = (n0 - 128) + wn*64 + ni*16 + lg*4;
            float4 b4 = *(const float4*)&bv[col];
            #pragma unroll
            for (int mi = 0; mi < 4; ++mi) {
                int m = m0 + wm*64 + mi*16 + lr;
                ushort4 o;
                o.x = f2bf(acc[ni][mi][0] + b4.x); o.y = f2bf(acc[ni][mi][1] + b4.y);
                o.z = f2bf(acc[ni][mi][2] + b4.z); o.w = f2bf(acc[ni][mi][3] + b4.w);
                *(ushort4*)&Out[(size_t)m*Cc + col] = o;
            }
        }
    }
}

// ---------------- V transposes: vcol[b][j][c][k]=V[k*128+j][c], vrow[b][i][c][k]=V[i*128+k][c] ----
__global__ __launch_bounds__(256) void vtrans(
    const unsigned short* __restrict__ vbf,
    unsigned short* __restrict__ vcol, unsigned short* __restrict__ vrow)
{
    const int L  = blockIdx.x;
    const int ct = blockIdx.y;
    const int bz = blockIdx.z;
    const int b = bz >> 1, mode = bz & 1;
    const int tid = threadIdx.x;
    const int lk = tid & 15;
    const int lc = tid >> 4;
    const int c0 = ct*128 + lc*8;
    const unsigned short* src = vbf + (size_t)b*HW*Cc;

    short8 in[8];
    #pragma unroll
    for (int u = 0; u < 8; ++u) {
        int k = lk*8 + u;
        int row = mode ? L*128 + k : k*128 + L;
        in[u] = *(const short8*)&src[(size_t)row*Cc + c0];
    }
    unsigned short* dst = (mode ? vrow : vcol) + (((size_t)(b*128 + L))*Cc + c0)*128 + lk*8;
    #pragma unroll
    for (int t = 0; t < 8; ++t) {
        short8 o;
        #pragma unroll
        for (int u = 0; u < 8; ++u) o[u] = in[u][t];
        *(short8*)&dst[(size_t)t*128] = o;
    }
}

// ---------------- criss-cross scores, bf16 MFMA (A=K, B=Q), coalesced e-writes ----------------
// e[((b*2+mode)*128+L)][r][k] = sum_c Q[line r][c] * K[line k][c]
__global__ __launch_bounds__(256) void cc_scores_mfma(
    const unsigned short* __restrict__ qbf, const unsigned short* __restrict__ kbf,
    float* __restrict__ e)
{
    const int L = blockIdx.x, mode = blockIdx.y, b = blockIdx.z;
    const unsigned short* qb = qbf + (size_t)b*HW*CQ;
    const unsigned short* kb = kbf + (size_t)b*HW*CQ;
    float* eb = e + ((size_t)((b*2+mode)*128 + L))*16384;

    __shared__ __align__(16) char smem[36864];
    auto Qs = (unsigned short (*)[72])smem;            // 128x72 ush
    auto Ks = (unsigned short (*)[72])(smem + 18432);  // 128x72 ush
    auto St = (float (*)[128])smem;                    // 64x128 f32 (aliases)

    const int tid = threadIdx.x;
    const int wid = tid >> 6, lane = tid & 63;
    const int wa = wid >> 1, wb_ = wid & 1;
    const int lr = lane & 15, lg = lane >> 4;

    #pragma unroll
    for (int r4 = 0; r4 < 4; ++r4) {
        int id = tid + r4*256;
        int row = id >> 3, ch = id & 7;
        int n = mode ? (L*128 + row) : (row*128 + L);
        *(short8*)&Qs[row][ch*8] = *(const short8*)&qb[(size_t)n*CQ + ch*8];
        *(short8*)&Ks[row][ch*8] = *(const short8*)&kb[(size_t)n*CQ + ch*8];
    }
    __syncthreads();

    f32x4 acc[4][4];                            // [ai(k)][bi(r)]
    #pragma unroll
    for (int i = 0; i < 4; ++i)
        #pragma unroll
        for (int j = 0; j < 4; ++j) acc[i][j] = (f32x4){0.f,0.f,0.f,0.f};

    #pragma unroll
    for (int ks = 0; ks < 2; ++ks) {
        short8 af[4], bf[4];
        #pragma unroll
        for (int ai = 0; ai < 4; ++ai) af[ai] = *(const short8*)&Ks[wa*64 + ai*16 + lr][ks*32 + lg*8];
        #pragma unroll
        for (int bi = 0; bi < 4; ++bi) bf[bi] = *(const short8*)&Qs[wb_*64 + bi*16 + lr][ks*32 + lg*8];
        #pragma unroll
        for (int ai = 0; ai < 4; ++ai)
            #pragma unroll
            for (int bi = 0; bi < 4; ++bi)
                acc[ai][bi] = __builtin_amdgcn_mfma_f32_16x16x32_bf16(af[ai], bf[bi], acc[ai][bi], 0, 0, 0);
    }

    #pragma unroll
    for (int s = 0; s < 2; ++s) {               // r-half
        __syncthreads();
        if (wb_ == s) {
            #pragma unroll
            for (int ai = 0; ai < 4; ++ai)
                #pragma unroll
                for (int bi = 0; bi < 4; ++bi) {
                    int ml = bi*16 + lr;
                    int cl = (wa*64 + ai*16 + lg*4) ^ ((ml & 7) << 2);
                    *(f32x4*)&St[ml][cl] = acc[ai][bi];
                }
        }
        __syncthreads();
        #pragma unroll
        for (int it = 0; it < 8; ++it) {
            int ml = it*8 + (tid >> 5);
            int cl = (tid & 31) * 4;
            f32x4 v = *(f32x4*)&St[ml][cl ^ ((ml & 7) << 2)];
            *(float4*)&eb[(size_t)(s*64 + ml)*128 + cl] = *(float4*)&v;
        }
    }
}

// ---------------- softmax over axis i; fp32 in -> bf16 att out ----------------
__global__ __launch_bounds__(128) void cc_softmax(const float* __restrict__ e,
                                                  unsigned short* __restrict__ attb)
{
    const int L = blockIdx.x, mode = blockIdx.y, b = blockIdx.z;
    const int k = threadIdx.x;
    size_t off; int stride;
    if (mode == 0) { off = ((size_t)(b*2)*128 + L)*16384 + k;        stride = 128;   }
    else           { off = ((size_t)(b*2+1)*128)*16384 + L*128 + k;  stride = 16384; }
    const float* base = e + off;
    unsigned short* ob = attb + off;
    float m = -1e30f, s = 0.f;
    #pragma unroll 8
    for (int i = 0; i < 128; ++i) {
        float val = base[i*stride];
        float mn = fmaxf(m, val);
        s = s*__expf(m - mn) + __expf(val - mn);
        m = mn;
    }
    float inv = 1.f / s;
    #pragma unroll 8
    for (int i = 0; i < 128; ++i) {
        float val = base[i*stride];
        ob[i*stride] = f2bf(__expf(val - m) * inv);
    }
}

// ---------------- fused depthwise conv + residual: 2 output rows/thread ----------------
__global__ __launch_bounds__(256) void cnn_resid(
    const unsigned short* __restrict__ xb16, const float* __restrict__ wtc, float* __restrict__ out)
{
    const int tid = threadIdx.x;
    const int c0  = (tid & 127) * 4;
    const int s   = tid >> 7;
    const int bx  = blockIdx.x;                    // 0..511
    const int w   = ((bx & 7) << 6) | (bx >> 3);   // XCD-chunked bijection (512 = 8 x 64)
    const int unit = w*2 + s;                      // 0..1023: 64 i-pairs x 16 j-strips
    const int b   = blockIdx.z;
    const int i0  = (unit >> 4) * 2;
    const int j0  = (unit & 15) * 8;
    const unsigned short* xb = xb16 + (size_t)b*HW*Cc;

    float4 bias = *(const float4*)&wtc[49*Cc + c0];
    float4 acc0[8], acc1[8];
    #pragma unroll
    for (int t = 0; t < 8; ++t) { acc0[t] = bias; acc1[t] = bias; }

    #pragma unroll
    for (int u8 = 0; u8 < 8; ++u8) {               // ii = i0-3 .. i0+4
        int ii = i0 - 3 + u8;
        if (ii >= 0 && ii < Hh) {
            float4 xv[14];
            #pragma unroll
            for (int u = 0; u < 14; ++u) {
                int jj = j0 - 3 + u;
                if (jj >= 0 && jj < Ww) {
                    ushort4 uu = *(const ushort4*)&xb[(size_t)(ii*Ww + jj)*Cc + c0];
                    xv[u].x = bf2f(uu.x); xv[u].y = bf2f(uu.y);
                    xv[u].z = bf2f(uu.z); xv[u].w = bf2f(uu.w);
                } else { xv[u].x = 0.f; xv[u].y = 0.f; xv[u].z = 0.f; xv[u].w = 0.f; }
            }
            if (u8 == 3) {                          // residual for row i0
                #pragma unroll
                for (int t = 0; t < 8; ++t) {
                    acc0[t].x += xv[t+3].x; acc0[t].y += xv[t+3].y;
                    acc0[t].z += xv[t+3].z; acc0[t].w += xv[t+3].w;
                }
            }
            if (u8 == 4) {                          // residual for row i0+1
                #pragma unroll
                for (int t = 0; t < 8; ++t) {
                    acc1[t].x += xv[t+3].x; acc1[t].y += xv[t+3].y;
                    acc1[t].z += xv[t+3].z; acc1[t].w += xv[t+3].w;
                }
            }
            if (u8 < 7) {                           // tap row d0=u8 for output i0
                #pragma unroll
                for (int dj = 0; dj < 7; ++dj) {
                    float4 w4 = *(const float4*)&wtc[(u8*7 + dj)*Cc + c0];
                    #pragma unroll
                    for (int t = 0; t < 8; ++t) {
                        acc0[t].x = fmaf(xv[t+dj].x, w4.x, acc0[t].x);
                        acc0[t].y = fmaf(xv[t+dj].y, w4.y, acc0[t].y);
                        acc0[t].z = fmaf(xv[t+dj].z, w4.z, acc0[t].z);
                        acc0[t].w = fmaf(xv[t+dj].w, w4.w, acc0[t].w);
                    }
                }
            }
            if (u8 >= 1) {                          // tap row d1=u8-1 for output i0+1
                #pragma unroll
                for (int dj = 0; dj < 7; ++dj) {
                    float4 w4 = *(const float4*)&wtc[((u8-1)*7 + dj)*Cc + c0];
                    #pragma unroll
                    for (int t = 0; t < 8; ++t) {
                        acc1[t].x = fmaf(xv[t+dj].x, w4.x, acc1[t].x);
                        acc1[t].y = fmaf(xv[t+dj].y, w4.y, acc1[t].y);
                        acc1[t].z = fmaf(xv[t+dj].z, w4.z, acc1[t].z);
                        acc1[t].w = fmaf(xv[t+dj].w, w4.w, acc1[t].w);
                    }
                }
            }
        }
    }

    #pragma unroll
    for (int t = 0; t < 8; ++t) {
        *(float4*)&out[((size_t)b*HW + i0*Ww + j0 + t)*Cc + c0]     = acc0[t];
        *(float4*)&out[((size_t)b*HW + (i0+1)*Ww + j0 + t)*Cc + c0] = acc1[t];
    }
}

// ---------------- aggregation, bf16 MFMA + LDS-staged coalesced epilogue ----------------
__global__ __launch_bounds__(256) void cc_agg_mfma(
    const unsigned short* __restrict__ attb, const unsigned short* __restrict__ vt,
    const float* __restrict__ base, float* __restrict__ dest,
    unsigned short* __restrict__ bfdup,
    const float* __restrict__ gamma_ptr, const int mode)
{
    const int L  = blockIdx.x;
    const int c0 = blockIdx.y * 128;
    const int b  = blockIdx.z;
    const unsigned short* A = vt + (((size_t)(b*128 + L))*Cc + c0)*128;
    const unsigned short* Bm = attb + ((size_t)((b*2+mode)*128 + L))*16384;

    __shared__ __align__(16) char smem[36864];
    auto Vl = (unsigned short (*)[72])smem;
    auto Ml = (unsigned short (*)[72])(smem + 18432);
    auto St = (float (*)[128])smem;

    const int tid = threadIdx.x;
    const int wid = tid >> 6, lane = tid & 63;
    const int wc = wid >> 1, wm = wid & 1;
    const int lr = lane & 15, lg = lane >> 4;

    f32x4 acc[4][4];
    #pragma unroll
    for (int i = 0; i < 4; ++i)
        #pragma unroll
        for (int j = 0; j < 4; ++j) acc[i][j] = (f32x4){0.f,0.f,0.f,0.f};

    for (int k0 = 0; k0 < 128; k0 += 64) {
        __syncthreads();
        #pragma unroll
        for (int r = 0; r < 4; ++r) {
            int id = tid + r*256;
            int row = id >> 3, ch = id & 7;
            *(short8*)&Vl[row][ch*8] = *(const short8*)&A[(size_t)row*128 + k0 + ch*8];
            *(short8*)&Ml[row][ch*8] = *(const short8*)&Bm[(size_t)row*128 + k0 + ch*8];
        }
        __syncthreads();
        #pragma unroll
        for (int ks = 0; ks < 2; ++ks) {
            short8 af[4], bf[4];
            #pragma unroll
            for (int ci = 0; ci < 4; ++ci) af[ci] = *(const short8*)&Vl[wc*64 + ci*16 + lr][ks*32 + lg*8];
            #pragma unroll
            for (int mi = 0; mi < 4; ++mi) bf[mi] = *(const short8*)&Ml[wm*64 + mi*16 + lr][ks*32 + lg*8];
            #pragma unroll
            for (int ci = 0; ci < 4; ++ci)
                #pragma unroll
                for (int mi = 0; mi < 4; ++mi)
                    acc[ci][mi] = __builtin_amdgcn_mfma_f32_16x16x32_bf16(af[ci], bf[mi], acc[ci][mi], 0, 0, 0);
        }
    }

    const float g = gamma_ptr[0];
    #pragma unroll
    for (int s = 0; s < 2; ++s) {
        __syncthreads();
        if (wm == s) {
            #pragma unroll
            for (int ci = 0; ci < 4; ++ci)
                #pragma unroll
                for (int mi = 0; mi < 4; ++mi) {
                    int ml = mi*16 + lr;
                    int cl = (wc*64 + ci*16 + lg*4) ^ ((ml & 7) << 2);
                    *(f32x4*)&St[ml][cl] = acc[ci][mi];
                }
        }
        __syncthreads();
        #pragma unroll
        for (int it = 0; it < 8; ++it) {
            int ml = it*8 + (tid >> 5);
            int cl = (tid & 31) * 4;
            int m  = s*64 + ml;
            int ns = mode ? (L*128 + m) : (m*128 + L);
            size_t off = ((size_t)b*HW + ns)*Cc + c0 + cl;
            f32x4 v = *(f32x4*)&St[ml][cl ^ ((ml & 7) << 2)];
            float4 bs = *(const float4*)&base[off];
            float4 o;
            o.x = bs.x + g*v[0]; o.y = bs.y + g*v[1];
            o.z = bs.z + g*v[2]; o.w = bs.w + g*v[3];
            *(float4*)&dest[off] = o;
            if (bfdup) {
                ushort4 d;
                d.x = f2bf(o.x); d.y = f2bf(o.y); d.z = f2bf(o.z); d.w = f2bf(o.w);
                *(ushort4*)&bfdup[off] = d;
            }
        }
    }
}

extern "C" void kernel_launch(void* const* d_in, const int* in_sizes, int n_in,
                              void* d_out, int out_size, void* d_ws, size_t ws_size,
                              hipStream_t stream)
{
    const float* x     = (const float*)d_in[0];
    const float* wq    = (const float*)d_in[1];
    const float* bq    = (const float*)d_in[2];
    const float* wk    = (const float*)d_in[3];
    const float* bk    = (const float*)d_in[4];
    const float* wv    = (const float*)d_in[5];
    const float* bv    = (const float*)d_in[6];
    const float* gamma = (const float*)d_in[7];
    const float* wq1   = (const float*)d_in[8];
    const float* bq1   = (const float*)d_in[9];
    const float* wk1   = (const float*)d_in[10];
    const float* bk1   = (const float*)d_in[11];
    const float* wv1   = (const float*)d_in[12];
    const float* bv1   = (const float*)d_in[13];
    const float* gamma1= (const float*)d_in[14];
    const float* w7    = (const float*)d_in[15];
    const float* b7    = (const float*)d_in[16];
    const float* w5    = (const float*)d_in[17];
    const float* b5    = (const float*)d_in[18];
    const float* w3    = (const float*)d_in[19];
    const float* b3    = (const float*)d_in[20];
    float* outp = (float*)d_out;

    float* ws = (float*)d_ws;
    float* eb  = ws;
    float* wtc = eb + (size_t)2*2*128*16384;
    unsigned short* xbf  = (unsigned short*)(wtc + 50*Cc);
    unsigned short* wb0  = xbf + (size_t)2*HW*Cc;
    unsigned short* wb1  = wb0 + (size_t)640*Cc;
    unsigned short* qbf  = wb1 + (size_t)640*Cc;
    unsigned short* kbf  = qbf + (size_t)2*HW*CQ;
    unsigned short* vbf  = kbf + (size_t)2*HW*CQ;
    unsigned short* attb = vbf;                       // alias (vbf dead after vtrans)
    unsigned short* vcol = vbf + (size_t)2*HW*Cc;
    unsigned short* vrow = vcol + (size_t)2*HW*Cc;
    float* ob = outp;   // block-1 intermediate lives in d_out

    prep_weights<<<dim3(2), dim3(256), 0, stream>>>(w7,b7,w5,b5,w3,b3, wtc);
    prep_wbf    <<<dim3(320), dim3(256), 0, stream>>>(wq, wk, wv, wb0);
    prep_wbf    <<<dim3(320), dim3(256), 0, stream>>>(wq1, wk1, wv1, wb1);
    to_bf16     <<<dim3(2048), dim3(256), 0, stream>>>(x, xbf, 2*HW*Cc);

    // ---- criss-cross block 1 (input x) ----
    qkv_gemm_mfma<<<dim3(128,5,2), dim3(256), 0, stream>>>((const short*)xbf, (const short*)wb0,
                                                           bq,bk,bv, qbf,kbf, vbf);
    vtrans        <<<dim3(128,4,4),  dim3(256), 0, stream>>>(vbf, vcol, vrow);
    cc_scores_mfma<<<dim3(128,2,2),  dim3(256), 0, stream>>>(qbf, kbf, eb);
    cc_softmax    <<<dim3(128,2,2),  dim3(128), 0, stream>>>(eb, attb);      // clobbers vbf (dead)
    cnn_resid     <<<dim3(512,1,2),  dim3(256), 0, stream>>>(xbf, wtc, ob);  // ob = x + cnn_feat1
    cc_agg_mfma   <<<dim3(128,4,2),  dim3(256), 0, stream>>>(attb, vcol, ob, ob, nullptr, gamma, 0);
    cc_agg_mfma   <<<dim3(128,4,2),  dim3(256), 0, stream>>>(attb, vrow, ob, ob, xbf,    gamma, 1);

    // ---- criss-cross block 2 (input ob via xbf dup, residual ob, output d_out) ----
    qkv_gemm_mfma<<<dim3(128,5,2), dim3(256), 0, stream>>>((const short*)xbf, (const short*)wb1,
                                                           bq1,bk1,bv1, qbf,kbf, vbf);
    vtrans        <<<dim3(128,4,4),  dim3(256), 0, stream>>>(vbf, vcol, vrow);
    cc_scores_mfma<<<dim3(128,2,2),  dim3(256), 0, stream>>>(qbf, kbf, eb);
    cc_softmax    <<<dim3(128,2,2),  dim3(128), 0, stream>>>(eb, attb);
    cc_agg_mfma   <<<dim3(128,4,2),  dim3(256), 0, stream>>>(attb, vcol, ob,   outp, nullptr, gamma1, 0);
    cc_agg_mfma   <<<dim3(128,4,2),  dim3(256), 0, stream>>>(attb, vrow, outp, outp, nullptr, gamma1, 1);
}